// Round 7
// baseline (280.247 us; speedup 1.0000x reference)
//
#include <hip/hip_runtime.h>
#include <math.h>

#define B_DIM 4096
#define S_DIM 200
#define E_DIM 100
#define C_DIM 20
#define K_DIM 51
#define PADW  25
#define V_DIM 50000

typedef _Float16 f16x8 __attribute__((ext_vector_type(8)));
typedef float    f32x4 __attribute__((ext_vector_type(4)));
typedef float    f32x2 __attribute__((ext_vector_type(2)));

// gT: 250 rows x 128B (img0 64B | img1 64B), XOR-swizzled in 16B groups by
// (row & 7) (r3: conflicts -> 0, correctness verified).
#define GT_ROWS   250
#define GT_STRIDE 128
#define GT_BYTES  (GT_ROWS * GT_STRIDE)   // 32000
#define NA_FRAGS  (K_DIM*2*2)    // (k, img, mt)
#define NA_SHORTS (NA_FRAGS*512) // 104448

// workspace layout (bytes); tiers guarded by ws_size at launch (r4 lesson:
// never write workspace beyond ws_size).
#define OFF_LT    208896u                 // 2000 floats
#define OFF_RNL   216896u                 // 20 floats
#define OFF_WC    216976u                 // 100x72 floats (28800 B)
#define OFF_GP    245776u                 // 50000 x 128B packed g rows (6.4 MB)
#define OFF_EW    6645776u                // 50000 x 256B (64-float rows, 12.8 MB)
#define NEED_G    6645776u
#define NEED_FULL 19445776u

// ---------------------------------------------------------------------------
// Prep 1 (verified): packed-K A-fragments (fp16 split x256, MFMA lane order);
// Lt[e*20+c]; rnl[c]; Wc[e*72+o] combined weight columns for vocab_kernel2
// (o<20: labels, 20<=o<70: w1, else 0).
// ---------------------------------------------------------------------------
__global__ void prep_kernel(const float* __restrict__ conv_w,
                            const float* __restrict__ labels,
                            const float* __restrict__ w1,
                            short* __restrict__ wA,
                            float* __restrict__ Lt,
                            float* __restrict__ rnl,
                            float* __restrict__ Wc) {
    int idx = blockIdx.x * 256 + threadIdx.x;
    if (idx < NA_SHORTS) {
        int frag = idx >> 9;           // ((k*2+img)*2+mt)
        int r    = idx & 511;
        int lane = r >> 3;
        int j    = r & 7;
        int mt   = frag & 1;
        int img  = (frag >> 1) & 1;
        int k    = frag >> 2;
        int o  = mt * 16 + (lane & 15);
        int kc = (lane >> 4) * 8 + j;  // K-col 0..31

        int i = -1, lo = 0;
        if (img == 0) {
            if (kc < 20) { i = kc;      lo = 0; }
            else         { i = kc - 20; lo = 1; }
        } else {
            if (kc < 8)       { i = 12 + kc; lo = 1; }
            else if (kc < 28) { i = kc - 8;  lo = 0; }
        }
        float v = 0.f;
        if (o < C_DIM && i >= 0) v = conv_w[(o * C_DIM + i) * K_DIM + k] * 256.f;
        _Float16 hi  = (_Float16)v;
        _Float16 val = lo ? (_Float16)(v - (float)hi) : hi;
        unsigned short bits;
        __builtin_memcpy(&bits, &val, 2);
        wA[idx] = (short)bits;
    } else if (idx < NA_SHORTS + C_DIM * E_DIM) {
        int t = idx - NA_SHORTS;
        int e = t / C_DIM, c = t % C_DIM;
        Lt[t] = labels[c * E_DIM + e];
    } else if (idx < NA_SHORTS + C_DIM * E_DIM + C_DIM) {
        int c = idx - NA_SHORTS - C_DIM * E_DIM;
        float s = 0.f;
        for (int e = 0; e < E_DIM; ++e) { float v = labels[c * E_DIM + e]; s += v * v; }
        float nn = sqrtf(s);
        rnl[c] = (nn > 0.f) ? 1.f / nn : 0.f;
    } else if (idx < NA_SHORTS + C_DIM * E_DIM + C_DIM + E_DIM * 72) {
        int t = idx - NA_SHORTS - C_DIM * E_DIM - C_DIM;
        int e = t / 72, o = t % 72;
        float v = 0.f;
        if (o < C_DIM)      v = labels[o * E_DIM + e];
        else if (o < 70)    v = w1[e * (E_DIM / 2) + (o - C_DIM)];
        Wc[t] = v;
    }
}

// ---------------------------------------------------------------------------
// Prep 2 (r7): output-parallel vocab precompute with paired-row ILP.
// r6 post-mortem: 1 row at a time + 2 waves/SIMD left the kernel
// latency-bound (~39us vs ~7us issue floor).  Now VCH=48 rows/block
// (preload amortized 2x) and each thread processes its 16 rows in PAIRS:
// two independent f32x4 accumulators (8 parallel FMA chains) per eb step.
// Per-row reduction order is bit-identical to r6 (passed).
//   threads: o = tid%72, roff = tid/72 (3 row-slices); tid>=216 idle.
//   o<20 -> label dot; 20<=o<70 -> EW[v][o-20]; o==70 -> ||emb||^2.
// ---------------------------------------------------------------------------
#define VCH 48
template <bool DO_EW>
__launch_bounds__(256, 2)
__global__ void vocab_kernel2(const float* __restrict__ emb,
                              const float* __restrict__ Wc,   // [100][72]
                              const float* __restrict__ rnl,
                              unsigned* __restrict__ Gpk,
                              float* __restrict__ EW) {
    __shared__ __align__(16) float embL[VCH][E_DIM];
    __shared__ float dL[VCH][C_DIM];
    __shared__ float n2L[VCH];
    __shared__ float rnlL[C_DIM];

    const int tid = threadIdx.x;
    const int v0  = blockIdx.x * VCH;

    if (tid < C_DIM) rnlL[tid] = rnl[tid];

    // stage 48 emb rows (1200 float4, coalesced)
    for (int i = tid; i < VCH * 25; i += 256) {
        const int r = i / 25, c4 = i % 25;
        const int v = v0 + r;
        float4 val{0.f, 0.f, 0.f, 0.f};
        if (v < V_DIM) val = ((const float4*)(emb + (size_t)v * E_DIM))[c4];
        ((float4*)&embL[r][0])[c4] = val;
    }
    __syncthreads();

    const int o    = tid % 72;
    const int roff = tid / 72;
    if (roff < 3) {
        // register-resident weight column (coalesced row reads, once)
        f32x4 wcv[25];
#pragma unroll
        for (int eb = 0; eb < 25; ++eb) {
            f32x4 w;
            w[0] = Wc[(eb * 4 + 0) * 72 + o];
            w[1] = Wc[(eb * 4 + 1) * 72 + o];
            w[2] = Wc[(eb * 4 + 2) * 72 + o];
            w[3] = Wc[(eb * 4 + 3) * 72 + o];
            wcv[eb] = w;
        }
        // 8 pairs: rows (roff+6gp, roff+6gp+3) -> covers roff+3t, t=0..15
#pragma unroll
        for (int gp = 0; gp < 8; ++gp) {
            const int r0 = roff + gp * 6;
            const int r1 = r0 + 3;
            const f32x4* e0 = (const f32x4*)&embL[r0][0];
            const f32x4* e1 = (const f32x4*)&embL[r1][0];
            f32x4 aA{0.f, 0.f, 0.f, 0.f}, aB{0.f, 0.f, 0.f, 0.f};
            if (o == 70) {
#pragma unroll
                for (int eb = 0; eb < 25; ++eb) {
                    const f32x4 x0 = e0[eb], x1 = e1[eb];
                    aA += x0 * x0; aB += x1 * x1;
                }
                n2L[r0] = aA[0] + aA[1] + aA[2] + aA[3];
                n2L[r1] = aB[0] + aB[1] + aB[2] + aB[3];
            } else if (o < 70) {
#pragma unroll
                for (int eb = 0; eb < 25; ++eb) {
                    const f32x4 x0 = e0[eb], x1 = e1[eb];
                    aA += x0 * wcv[eb]; aB += x1 * wcv[eb];
                }
                const float sA = aA[0] + aA[1] + aA[2] + aA[3];
                const float sB = aB[0] + aB[1] + aB[2] + aB[3];
                if (o < C_DIM) { dL[r0][o] = sA; dL[r1][o] = sB; }
                else if (DO_EW) {
                    if (v0 + r0 < V_DIM) EW[(size_t)(v0 + r0) * 64 + (o - C_DIM)] = sA;
                    if (v0 + r1 < V_DIM) EW[(size_t)(v0 + r1) * 64 + (o - C_DIM)] = sB;
                }
            }
        }
    }
    __syncthreads();

    // pack phase: one thread per row builds the 128B Gpk line (r5-verified)
    if (tid < VCH) {
        const int v = v0 + tid;
        if (v < V_DIM) {
            const float n2 = n2L[tid];
            const float xn = sqrtf(n2);
            const float rxn16 = (xn > 0.f) ? 16.f / xn : 0.f;
            unsigned short gh[C_DIM], gl[C_DIM];
#pragma unroll
            for (int c = 0; c < C_DIM; ++c) {
                float a = dL[tid][c] * rnlL[c] * rxn16;
                _Float16 h = (_Float16)a;
                _Float16 l = (_Float16)(a - (float)h);
                __builtin_memcpy(&gh[c], &h, 2);
                __builtin_memcpy(&gl[c], &l, 2);
            }
#define PK(a, b) ((unsigned)(a) | ((unsigned)(b) << 16))
            unsigned tv[32];
#pragma unroll
            for (int d = 0; d < 10; ++d) tv[d] = PK(gh[2 * d], gh[2 * d + 1]);
#pragma unroll
            for (int d = 0; d < 6; ++d)  tv[10 + d] = PK(gh[2 * d], gh[2 * d + 1]);
#pragma unroll
            for (int d = 0; d < 4; ++d)  tv[16 + d] = PK(gh[12 + 2 * d], gh[13 + 2 * d]);
#pragma unroll
            for (int d = 0; d < 10; ++d) tv[20 + d] = PK(gl[2 * d], gl[2 * d + 1]);
            tv[30] = 0u; tv[31] = 0u;
#undef PK
            uint4* go = (uint4*)(Gpk + (size_t)v * 32);
#pragma unroll
            for (int g = 0; g < 8; ++g) {
                uint4 q;
                q.x = tv[4 * g + 0]; q.y = tv[4 * g + 1];
                q.z = tv[4 * g + 2]; q.w = tv[4 * g + 3];
                go[g] = q;
            }
        }
    }
}

// ---------------------------------------------------------------------------
// Phase-ring conv (r0 structure, proven spill-free at 64 VGPR + AGPR acc).
// ---------------------------------------------------------------------------
template <int CNT>
__device__ __forceinline__ void conv_tiles(const short* __restrict__ wA,
                                           const char* rowbase,   // gT + (nt0*16+n)*GT_STRIDE
                                           f32x4 (&acc)[4][2],
                                           int lane) {
    const int n = lane & 15;
    const int q = lane >> 4;
#define LDFRAG(k, img, mt) (*(const f16x8*)(wA + (((k) * 2 + (img)) * 2 + (mt)) * 512 + lane * 8))
#pragma unroll
    for (int img = 0; img < 2; ++img) {
#pragma unroll 1
        for (int p = 0; p < 16; ++p) {
            f16x8 a0[4], a1[4];
#pragma unroll
            for (int j = 0; j < 4; ++j) {
                const int k = p + 16 * j;
                if (k < K_DIM) { a0[j] = LDFRAG(k, img, 0); a1[j] = LDFRAG(k, img, 1); }
            }
            const int off = (q * 16 + img * 64) ^ (((n + p) & 7) << 4);
            const char* rp = rowbase + p * GT_STRIDE + off;
            f16x8 ring[CNT + 3];
            const int nd = (p < 3) ? (CNT + 3) : (CNT + 2);
#pragma unroll
            for (int d = 0; d < CNT + 3; ++d) {
                if (d < nd)
                    ring[d] = *(const f16x8*)(rp + d * 16 * GT_STRIDE);
            }
#pragma unroll
            for (int j = 0; j < 4; ++j) {
                if (p + 16 * j < K_DIM) {
#pragma unroll
                    for (int t = 0; t < CNT; ++t) {
                        acc[t][0] = __builtin_amdgcn_mfma_f32_16x16x32_f16(a0[j], ring[t + j], acc[t][0], 0, 0, 0);
                        acc[t][1] = __builtin_amdgcn_mfma_f32_16x16x32_f16(a1[j], ring[t + j], acc[t][1], 0, 0, 0);
                    }
                }
            }
        }
    }
#undef LDFRAG
}

// ---------------------------------------------------------------------------
// Fused kernel, tiered (r5-verified):
//   PRE_G:  phase 1 gathers the precomputed 128B packed g row.
//   USE_EW: pooling in w1-space over precomputed EW rows; MLP layer 1 gone.
// ---------------------------------------------------------------------------
template <bool PRE_G, bool USE_EW>
__launch_bounds__(256, 4)
__global__ void fused_kernel(const int* __restrict__ x,
                             const int* __restrict__ mask,     // bool -> int32
                             const unsigned* __restrict__ Gpk,
                             const float* __restrict__ EW,
                             const float* __restrict__ emb,
                             const float* __restrict__ Lt,
                             const float* __restrict__ rnl,
                             const float* __restrict__ conv_b,
                             const float* __restrict__ w1,
                             const float* __restrict__ b1,
                             const float* __restrict__ w2,
                             const float* __restrict__ b2,
                             const short* __restrict__ wA,
                             float* __restrict__ out) {
    __shared__ __align__(16) char smem[GT_BYTES];   // gT, later aliased
    __shared__ unsigned short toks[S_DIM];

    short* gT   = (short*)smem;
    float* marr = (float*)(smem);            // [0,    800)   after conv
    float* red  = (float*)(smem + 1024);     // cross-wave scratch (8 floats)
    float* bw   = (float*)(smem + 2048);     // [2048, 2848)
    float* zp   = (float*)(smem + 3072);     // 4 x 100 (or 4 x 64)
    float* zsh  = (float*)(smem + 4672);
    float* hsh  = (float*)(smem + 5120);

    const int tid  = threadIdx.x;
    const int b    = blockIdx.x;
    const int lane = tid & 63;
    const int wv   = tid >> 6;
    const int n    = lane & 15;

    // ---- zero only the pad rows [0,25) and [225,250); rows 25..224 are
    // fully written by phase 1 (all 8 swizzled groups per row) ----
    {
        float4 z{0.f, 0.f, 0.f, 0.f};
        for (int i = tid; i < 50 * 8; i += 256) {
            const int rr  = i >> 3;
            const int row = (rr < 25) ? rr : rr + 200;
            ((float4*)(smem + row * GT_STRIDE))[i & 7] = z;
        }
    }

    const int s    = tid;
    const bool act = (s < S_DIM);
    int tok = 0, msk = 0;
    if (act) {
        tok = x[b * S_DIM + s];
        msk = mask[b * S_DIM + s];
        toks[s] = (unsigned short)tok;
    }
    __syncthreads();

    // ---- phase 1: packed g row -> swizzled LDS ----
    if (act) {
        const int row = PADW + s;
        const int h8  = row & 7;
        uint4* rw = (uint4*)(smem + row * GT_STRIDE);
        if (PRE_G) {
            const uint4* gp = (const uint4*)(Gpk + (size_t)tok * 32); // one 128B line
            uint4 t0 = gp[0], t1 = gp[1], t2 = gp[2], t3 = gp[3];
            uint4 t4 = gp[4], t5 = gp[5], t6 = gp[6], t7 = gp[7];
            rw[0 ^ h8] = t0; rw[1 ^ h8] = t1; rw[2 ^ h8] = t2; rw[3 ^ h8] = t3;
            rw[4 ^ h8] = t4; rw[5 ^ h8] = t5; rw[6 ^ h8] = t6; rw[7 ^ h8] = t7;
        } else {
            // verified r3 in-kernel cosine path
            f32x2 dacc2[10];
#pragma unroll
            for (int i = 0; i < 10; ++i) dacc2[i] = f32x2{0.f, 0.f};
            float n2 = 0.f;
            const float4* er  = (const float4*)(emb + (size_t)tok * E_DIM);
            const f32x2* Lt2 = (const f32x2*)Lt;
            for (int j = 0; j < 25; ++j) {
                const float4 r = er[j];
                n2 += r.x * r.x + r.y * r.y + r.z * r.z + r.w * r.w;
                const float rv[4] = {r.x, r.y, r.z, r.w};
#pragma unroll
                for (int u = 0; u < 4; ++u) {
                    const f32x2 xe = {rv[u], rv[u]};
                    const f32x2* Lrow = Lt2 + (j * 4 + u) * 10;
#pragma unroll
                    for (int i = 0; i < 10; ++i)
                        dacc2[i] += xe * Lrow[i];
                }
            }
            const float xn    = sqrtf(n2);
            const float rxn16 = (xn > 0.f) ? 16.f / xn : 0.f;

            unsigned short gh[C_DIM], gl[C_DIM];
#pragma unroll
            for (int c = 0; c < C_DIM; ++c) {
                float a = dacc2[c >> 1][c & 1] * rnl[c] * rxn16;
                _Float16 h = (_Float16)a;
                _Float16 l = (_Float16)(a - (float)h);
                __builtin_memcpy(&gh[c], &h, 2);
                __builtin_memcpy(&gl[c], &l, 2);
            }
#define PK(a, b) ((unsigned)(a) | ((unsigned)(b) << 16))
            unsigned tv[32];
#pragma unroll
            for (int d = 0; d < 10; ++d) tv[d] = PK(gh[2 * d], gh[2 * d + 1]);
#pragma unroll
            for (int d = 0; d < 6; ++d)  tv[10 + d] = PK(gh[2 * d], gh[2 * d + 1]);
#pragma unroll
            for (int d = 0; d < 4; ++d)  tv[16 + d] = PK(gh[12 + 2 * d], gh[13 + 2 * d]);
#pragma unroll
            for (int d = 0; d < 10; ++d) tv[20 + d] = PK(gl[2 * d], gl[2 * d + 1]);
            tv[30] = 0u; tv[31] = 0u;
#undef PK
#pragma unroll
            for (int g = 0; g < 8; ++g) {
                uint4 v;
                v.x = tv[4 * g + 0]; v.y = tv[4 * g + 1];
                v.z = tv[4 * g + 2]; v.w = tv[4 * g + 3];
                rw[g ^ h8] = v;
            }
        }
    }
    __syncthreads();

    // ---- conv: waves split the 13 n-tiles (4/3/3/3) ----
    f32x4 acc[4][2];
#pragma unroll
    for (int t = 0; t < 4; ++t) {
        acc[t][0] = f32x4{0.f, 0.f, 0.f, 0.f};
        acc[t][1] = f32x4{0.f, 0.f, 0.f, 0.f};
    }
    const int nt0 = (wv == 0) ? 0 : (1 + wv * 3);      // 0,4,7,10
    const int cnt = (wv == 0) ? 4 : 3;
    const char* rowbase = (const char*)gT + (nt0 * 16 + n) * GT_STRIDE;
    if (wv == 0) conv_tiles<4>(wA, rowbase, acc, lane);
    else         conv_tiles<3>(wA, rowbase, acc, lane);

    __syncthreads();   // gT dead; overlay becomes live

    // ---- epilogue: relu+bias+channel max -> marr[s] (static t indexing) ----
    {
        const int q = lane >> 4;
        const float inv = 1.f / 4096.f;
        float cb0[4], cb1[4];
#pragma unroll
        for (int r = 0; r < 4; ++r) {
            cb0[r] = conv_b[4 * q + r];
            cb1[r] = (q == 0) ? conv_b[16 + r] : 0.f;
        }
#pragma unroll
        for (int t = 0; t < 4; ++t) {
            if (t < cnt) {
                float m = 0.f;   // relu floor
#pragma unroll
                for (int r = 0; r < 4; ++r) m = fmaxf(m, acc[t][0][r] * inv + cb0[r]);
                if (q == 0) {
#pragma unroll
                    for (int r = 0; r < 4; ++r) m = fmaxf(m, acc[t][1][r] * inv + cb1[r]);
                }
                m = fmaxf(m, __shfl_xor(m, 16));
                m = fmaxf(m, __shfl_xor(m, 32));
                const int ss = (nt0 + t) * 16 + n;
                if (q == 0 && ss < S_DIM) marr[ss] = m;
            }
        }
    }
    __syncthreads();

    // ---- softmax over s: wave shuffles + 4-slot cross-wave ----
    {
        float mval = act ? ((msk != 0) ? marr[s] : -1e13f) : -1e30f;
        float lm = mval;
#pragma unroll
        for (int off = 32; off > 0; off >>= 1) lm = fmaxf(lm, __shfl_xor(lm, off));
        if (lane == 0) red[wv] = lm;
        __syncthreads();
        const float gmax = fmaxf(fmaxf(red[0], red[1]), fmaxf(red[2], red[3]));
        const float p = act ? expf(mval - gmax) : 0.f;
        float ps = p;
#pragma unroll
        for (int off = 32; off > 0; off >>= 1) ps += __shfl_xor(ps, off);
        if (lane == 0) red[4 + wv] = ps;
        __syncthreads();
        const float gsum = (red[4] + red[5]) + (red[6] + red[7]);
        if (act) bw[s] = p / gsum;
    }
    __syncthreads();

    if (USE_EW) {
        // ---- pooling in w1-space over EW rows; MLP1 precomputed ----
        {
            const bool pu = (lane < E_DIM / 2);
            float za = 0.f, zb = 0.f;
            const int s0 = wv * 50;
            for (int ss = s0; ss < s0 + 50; ss += 2) {
                const float  w0  = bw[ss];
                const float  w1v = bw[ss + 1];
                const float* r0 = EW + (size_t)toks[ss] * 64;
                const float* r1 = EW + (size_t)toks[ss + 1] * 64;
                if (pu) {
                    za += w0  * r0[lane];
                    zb += w1v * r1[lane];
                }
            }
            if (pu) zp[wv * 64 + lane] = za + zb;
        }
        __syncthreads();
        if (tid < E_DIM / 2) {
            const float h = zp[tid] + zp[64 + tid] + zp[128 + tid] + zp[192 + tid] + b1[tid];
            hsh[tid] = fmaxf(h, 0.f);
        }
        __syncthreads();
    } else {
        // ---- r3 pooling over emb + MLP layer 1 ----
        {
            float za0 = 0.f, zb0 = 0.f, za1 = 0.f, zb1 = 0.f;
            const int s0 = wv * 50;
            for (int ss = s0; ss < s0 + 50; ss += 2) {
                const float  w0  = bw[ss];
                const float  w1v = bw[ss + 1];
                const float* r0 = emb + (size_t)toks[ss] * E_DIM;
                const float* r1 = emb + (size_t)toks[ss + 1] * E_DIM;
                za0 += w0 * r0[lane];
                za1 += w1v * r1[lane];
                if (lane < E_DIM - 64) {
                    zb0 += w0 * r0[64 + lane];
                    zb1 += w1v * r1[64 + lane];
                }
            }
            zp[wv * E_DIM + lane] = za0 + za1;
            if (lane < E_DIM - 64) zp[wv * E_DIM + 64 + lane] = zb0 + zb1;
        }
        __syncthreads();
        if (tid < E_DIM)
            zsh[tid] = zp[tid] + zp[E_DIM + tid] + zp[2 * E_DIM + tid] + zp[3 * E_DIM + tid];
        __syncthreads();
        if (tid < E_DIM / 2) {
            float h = b1[tid];
            for (int e = 0; e < E_DIM; ++e) h += zsh[e] * w1[e * (E_DIM / 2) + tid];
            hsh[tid] = fmaxf(h, 0.f);
        }
        __syncthreads();
    }

    if (tid < C_DIM) {
        float o = b2[tid];
#pragma unroll
        for (int j = 0; j < E_DIM / 2; ++j) o += hsh[j] * w2[j * C_DIM + tid];
        out[b * C_DIM + tid] = o;
    }
}

// ---------------------------------------------------------------------------
extern "C" void kernel_launch(void* const* d_in, const int* in_sizes, int n_in,
                              void* d_out, int out_size, void* d_ws, size_t ws_size,
                              hipStream_t stream) {
    const int*   x      = (const int*)d_in[0];
    const int*   mask   = (const int*)d_in[2];    // bool delivered as int32
    const float* emb    = (const float*)d_in[3];
    const float* labels = (const float*)d_in[4];
    const float* conv_w = (const float*)d_in[5];
    const float* conv_b = (const float*)d_in[6];
    const float* w1     = (const float*)d_in[7];
    const float* b1     = (const float*)d_in[8];
    const float* w2     = (const float*)d_in[9];
    const float* b2     = (const float*)d_in[10];
    float*       out    = (float*)d_out;

    short*    wA  = (short*)d_ws;                         // 208896 B
    float*    Lt  = (float*)((char*)d_ws + OFF_LT);
    float*    rnl = (float*)((char*)d_ws + OFF_RNL);
    float*    Wc  = (float*)((char*)d_ws + OFF_WC);
    unsigned* Gpk = (unsigned*)((char*)d_ws + OFF_GP);
    float*    EW  = (float*)((char*)d_ws + OFF_EW);

    const int prep_n = NA_SHORTS + C_DIM * E_DIM + C_DIM + E_DIM * 72;
    prep_kernel<<<(prep_n + 255) / 256, 256, 0, stream>>>(conv_w, labels, w1,
                                                          wA, Lt, rnl, Wc);

    const int vg = (V_DIM + VCH - 1) / VCH;
    if (ws_size >= NEED_FULL) {
        vocab_kernel2<true><<<vg, 256, 0, stream>>>(emb, Wc, rnl, Gpk, EW);
        fused_kernel<true, true><<<B_DIM, 256, 0, stream>>>(
            x, mask, Gpk, EW, emb, Lt, rnl, conv_b, w1, b1, w2, b2, wA, out);
    } else if (ws_size >= NEED_G) {
        vocab_kernel2<false><<<vg, 256, 0, stream>>>(emb, Wc, rnl, Gpk, EW);
        fused_kernel<true, false><<<B_DIM, 256, 0, stream>>>(
            x, mask, Gpk, EW, emb, Lt, rnl, conv_b, w1, b1, w2, b2, wA, out);
    } else {
        fused_kernel<false, false><<<B_DIM, 256, 0, stream>>>(
            x, mask, Gpk, EW, emb, Lt, rnl, conv_b, w1, b1, w2, b2, wA, out);
    }
}

// Round 8
// 276.414 us; speedup vs baseline: 1.0139x; 1.0139x over previous
//
#include <hip/hip_runtime.h>
#include <math.h>

#define B_DIM 4096
#define S_DIM 200
#define E_DIM 100
#define C_DIM 20
#define K_DIM 51
#define PADW  25
#define V_DIM 50000

typedef _Float16 f16x8 __attribute__((ext_vector_type(8)));
typedef float    f32x4 __attribute__((ext_vector_type(4)));
typedef float    f32x2 __attribute__((ext_vector_type(2)));

// gT: 250 rows x 128B (img0 64B | img1 64B), XOR-swizzled in 16B groups by
// (row & 7) (r3: conflicts -> 0, correctness verified).
#define GT_ROWS   250
#define GT_STRIDE 128
#define GT_BYTES  (GT_ROWS * GT_STRIDE)   // 32000
#define NA_FRAGS  (K_DIM*2*2)    // (k, img, mt)
#define NA_SHORTS (NA_FRAGS*512) // 104448
#define NV_FRAGS  50             // 5 o-tiles x 10 K-chunks (vocab GEMM A)
#define NV_SHORTS (NV_FRAGS*512) // 25600

// workspace layout (bytes); tiers guarded by ws_size (r4 lesson).
#define OFF_WAV   208896u                 // vocab A-frags, 51200 B
#define OFF_LT    260096u                 // 2000 floats
#define OFF_RNL   268096u                 // 20 floats
#define OFF_GP    268176u                 // 50000 x 128B packed g rows (6.4 MB)
#define OFF_EW    6668176u                // 50000 x 52-float rows (10.4 MB)
#define NEED_G    6668176u
#define NEED_FULL 17068176u               // < r6's 19.45MB (proven available)

// ---------------------------------------------------------------------------
// Prep: conv A-frags (verified); Lt; rnl; vocab A-frags.
// Vocab A K-slot semantics (g = c*32 + kc):
//   g<100: hi(256*w[o][g])      (pairs with B hi_e)
//   g<200: hi(256*w[o][g-100])  (pairs with B lo_e)
//   g<300: lo(256*w[o][g-200])  (pairs with B hi_e)
//   else 0.   w[o][e]: o<20 -> labels[o][e]; 20<=o<70 -> w1[e][o-20]; else 0.
// ---------------------------------------------------------------------------
__global__ void prep_kernel(const float* __restrict__ conv_w,
                            const float* __restrict__ labels,
                            const float* __restrict__ w1,
                            short* __restrict__ wA,
                            short* __restrict__ wAv,
                            float* __restrict__ Lt,
                            float* __restrict__ rnl) {
    int idx = blockIdx.x * 256 + threadIdx.x;
    if (idx < NA_SHORTS) {
        int frag = idx >> 9;           // ((k*2+img)*2+mt)
        int r    = idx & 511;
        int lane = r >> 3;
        int j    = r & 7;
        int mt   = frag & 1;
        int img  = (frag >> 1) & 1;
        int k    = frag >> 2;
        int o  = mt * 16 + (lane & 15);
        int kc = (lane >> 4) * 8 + j;  // K-col 0..31

        int i = -1, lo = 0;
        if (img == 0) {
            if (kc < 20) { i = kc;      lo = 0; }
            else         { i = kc - 20; lo = 1; }
        } else {
            if (kc < 8)       { i = 12 + kc; lo = 1; }
            else if (kc < 28) { i = kc - 8;  lo = 0; }
        }
        float v = 0.f;
        if (o < C_DIM && i >= 0) v = conv_w[(o * C_DIM + i) * K_DIM + k] * 256.f;
        _Float16 hi  = (_Float16)v;
        _Float16 val = lo ? (_Float16)(v - (float)hi) : hi;
        unsigned short bits;
        __builtin_memcpy(&bits, &val, 2);
        wA[idx] = (short)bits;
    } else if (idx < NA_SHORTS + C_DIM * E_DIM) {
        int t = idx - NA_SHORTS;
        int e = t / C_DIM, c = t % C_DIM;
        Lt[t] = labels[c * E_DIM + e];
    } else if (idx < NA_SHORTS + C_DIM * E_DIM + C_DIM) {
        int c = idx - NA_SHORTS - C_DIM * E_DIM;
        float s = 0.f;
        for (int e = 0; e < E_DIM; ++e) { float v = labels[c * E_DIM + e]; s += v * v; }
        float nn = sqrtf(s);
        rnl[c] = (nn > 0.f) ? 1.f / nn : 0.f;
    } else if (idx < NA_SHORTS + C_DIM * E_DIM + C_DIM + NV_SHORTS) {
        int t    = idx - NA_SHORTS - C_DIM * E_DIM - C_DIM;
        int f    = t >> 9;             // ot*10 + c
        int r    = t & 511;
        int lane = r >> 3;
        int j    = r & 7;
        int ot   = f / 10;
        int c    = f % 10;
        int o    = ot * 16 + (lane & 15);
        int g    = c * 32 + (lane >> 4) * 8 + j;
        int e = -1, lo = 0;
        if (g < 100)      { e = g; }
        else if (g < 200) { e = g - 100; }
        else if (g < 300) { e = g - 200; lo = 1; }
        float w = 0.f;
        if (e >= 0 && o < 70)
            w = ((o < C_DIM) ? labels[o * E_DIM + e]
                             : w1[e * (E_DIM / 2) + (o - C_DIM)]) * 256.f;
        _Float16 h   = (_Float16)w;
        _Float16 val = lo ? (_Float16)(w - (float)h) : h;
        unsigned short bits;
        __builtin_memcpy(&bits, &val, 2);
        wAv[t] = (short)bits;
    }
}

// ---------------------------------------------------------------------------
// Vocab precompute as MFMA GEMM (r8).  r7 post-mortem: scalar vocab was
// LDS-pipe bound (~400 ds_read_b128/thread ~= 55us).  Per block: stage 64
// emb rows as a 320-slot hi/lo f16 K-image (x16 scale), 200 MFMAs compute
// all 72 outputs, acc/4096 -> Gpk pack (r5-verified bit path) + EW rows.
// Fragment conventions identical to the verified conv kernel:
//   A: o=lane&15, kc=(lane>>4)*8+j;  B: col=lane&15 (v), kc=(lane>>4)*8+j;
//   C: col=lane&15 (v), o=(lane>>4)*4+reg.
// ---------------------------------------------------------------------------
template <bool DO_EW>
__launch_bounds__(256, 3)
__global__ void vocab_mfma(const float* __restrict__ emb,
                           const short* __restrict__ wAv,
                           const float* __restrict__ rnl,
                           unsigned* __restrict__ Gpk,
                           float* __restrict__ EW) {
    __shared__ __align__(16) char BIMG[64 * 640];   // 64 v-rows x 320 f16
    __shared__ float nP[64][4];
    __shared__ float rnlL[C_DIM];
    float* dL = (float*)BIMG;              // [64][20], alias after MFMA
    float* eL = (float*)(BIMG + 5120);     // [64][52], alias after MFMA

    const int tid = threadIdx.x;
    const int v0  = blockIdx.x * 64;

    if (tid < C_DIM) rnlL[tid] = rnl[tid];
    // zero B-image (pad slots 300-319 must be 0, not garbage/NaN)
    {
        uint4 z{0u, 0u, 0u, 0u};
        uint4* p = (uint4*)BIMG;
        for (int i = tid; i < 2560; i += 256) p[i] = z;
    }
    __syncthreads();

    // stage: thread (v4=tid>>2, q4=tid&3) packs e in [q4*25, q4*25+25)
#define BPUT(v, g, val) do {                                                  \
        int _grp = (g) >> 3;                                                  \
        int _swz = (_grp & ~7) | ((_grp & 7) ^ ((v) & 7));                    \
        *(_Float16*)(BIMG + (v) * 640 + _swz * 16 + ((g) & 7) * 2) = (val);   \
    } while (0)
    {
        const int v4 = tid >> 2, q4 = tid & 3;
        const int vg = v0 + v4;
        const bool ok = (vg < V_DIM);
        const float* er = emb + (size_t)(ok ? vg : 0) * E_DIM + q4 * 25;
        float sq = 0.f;
        for (int i = 0; i < 25; ++i) {
            const float f = ok ? er[i] : 0.f;
            sq += f * f;
            const float fs = f * 16.f;
            _Float16 h = (_Float16)fs;
            _Float16 l = (_Float16)(fs - (float)h);
            const int e = q4 * 25 + i;
            BPUT(v4, e, h);
            BPUT(v4, 100 + e, l);
            BPUT(v4, 200 + e, h);
        }
        nP[v4][q4] = sq;
    }
#undef BPUT
    __syncthreads();

    // MFMA: wave wv owns v-tile wv (16 v); 5 o-tiles x 10 K-chunks
    const int lane = tid & 63;
    const int wv   = tid >> 6;
    const int n    = lane & 15;
    const int q    = lane >> 4;
    f32x4 acc5[5];
#pragma unroll
    for (int ot = 0; ot < 5; ++ot) acc5[ot] = f32x4{0.f, 0.f, 0.f, 0.f};
    {
        const int vrow = wv * 16 + n;
        const char* rb = BIMG + vrow * 640;
        const int vx = vrow & 7;
#pragma unroll
        for (int c = 0; c < 10; ++c) {
            const int grp = c * 4 + q;
            const int swz = (grp & ~7) | ((grp & 7) ^ vx);
            const f16x8 bf = *(const f16x8*)(rb + swz * 16);
#pragma unroll
            for (int ot = 0; ot < 5; ++ot) {
                const f16x8 af = *(const f16x8*)(wAv + (ot * 10 + c) * 512 + lane * 8);
                acc5[ot] = __builtin_amdgcn_mfma_f32_16x16x32_f16(af, bf, acc5[ot], 0, 0, 0);
            }
        }
    }
    __syncthreads();   // B-image dead; dL/eL overlay live

    // scatter acc (o = ot*16 + q*4 + r, v = wv*16 + n), scaled /4096
    {
        const float inv = 1.f / 4096.f;
        const int v4 = wv * 16 + n;
#pragma unroll
        for (int ot = 0; ot < 5; ++ot) {
#pragma unroll
            for (int r = 0; r < 4; ++r) {
                const int o = ot * 16 + q * 4 + r;
                const float val = acc5[ot][r] * inv;
                if (o < C_DIM) dL[v4 * 20 + o] = val;
                else if (o < 70) { if (DO_EW) eL[v4 * 52 + (o - 20)] = val; }
            }
        }
    }
    __syncthreads();

    // pack: one thread per v builds the 128B Gpk line (r5-verified bits) + EW
    if (tid < 64) {
        const int vg = v0 + tid;
        if (vg < V_DIM) {
            const float n2 = nP[tid][0] + nP[tid][1] + nP[tid][2] + nP[tid][3];
            const float xn = sqrtf(n2);
            const float rxn16 = (xn > 0.f) ? 16.f / xn : 0.f;
            unsigned short gh[C_DIM], gl[C_DIM];
#pragma unroll
            for (int c = 0; c < C_DIM; ++c) {
                float a = dL[tid * 20 + c] * rnlL[c] * rxn16;
                _Float16 h = (_Float16)a;
                _Float16 l = (_Float16)(a - (float)h);
                __builtin_memcpy(&gh[c], &h, 2);
                __builtin_memcpy(&gl[c], &l, 2);
            }
#define PK(a, b) ((unsigned)(a) | ((unsigned)(b) << 16))
            unsigned tv[32];
#pragma unroll
            for (int d = 0; d < 10; ++d) tv[d] = PK(gh[2 * d], gh[2 * d + 1]);
#pragma unroll
            for (int d = 0; d < 6; ++d)  tv[10 + d] = PK(gh[2 * d], gh[2 * d + 1]);
#pragma unroll
            for (int d = 0; d < 4; ++d)  tv[16 + d] = PK(gh[12 + 2 * d], gh[13 + 2 * d]);
#pragma unroll
            for (int d = 0; d < 10; ++d) tv[20 + d] = PK(gl[2 * d], gl[2 * d + 1]);
            tv[30] = 0u; tv[31] = 0u;
#undef PK
            uint4* go = (uint4*)(Gpk + (size_t)vg * 32);
#pragma unroll
            for (int g = 0; g < 8; ++g) {
                uint4 qv;
                qv.x = tv[4 * g + 0]; qv.y = tv[4 * g + 1];
                qv.z = tv[4 * g + 2]; qv.w = tv[4 * g + 3];
                go[g] = qv;
            }
            if (DO_EW) {
                float4* eo = (float4*)(EW + (size_t)vg * 52);
                const float4* ei = (const float4*)(eL + tid * 52);
#pragma unroll
                for (int w4 = 0; w4 < 13; ++w4) eo[w4] = ei[w4];
            }
        }
    }
}

// ---------------------------------------------------------------------------
// Phase-ring conv (r0 structure, proven spill-free at 64 VGPR + AGPR acc).
// ---------------------------------------------------------------------------
template <int CNT>
__device__ __forceinline__ void conv_tiles(const short* __restrict__ wA,
                                           const char* rowbase,   // gT + (nt0*16+n)*GT_STRIDE
                                           f32x4 (&acc)[4][2],
                                           int lane) {
    const int n = lane & 15;
    const int q = lane >> 4;
#define LDFRAG(k, img, mt) (*(const f16x8*)(wA + (((k) * 2 + (img)) * 2 + (mt)) * 512 + lane * 8))
#pragma unroll
    for (int img = 0; img < 2; ++img) {
#pragma unroll 1
        for (int p = 0; p < 16; ++p) {
            f16x8 a0[4], a1[4];
#pragma unroll
            for (int j = 0; j < 4; ++j) {
                const int k = p + 16 * j;
                if (k < K_DIM) { a0[j] = LDFRAG(k, img, 0); a1[j] = LDFRAG(k, img, 1); }
            }
            const int off = (q * 16 + img * 64) ^ (((n + p) & 7) << 4);
            const char* rp = rowbase + p * GT_STRIDE + off;
            f16x8 ring[CNT + 3];
            const int nd = (p < 3) ? (CNT + 3) : (CNT + 2);
#pragma unroll
            for (int d = 0; d < CNT + 3; ++d) {
                if (d < nd)
                    ring[d] = *(const f16x8*)(rp + d * 16 * GT_STRIDE);
            }
#pragma unroll
            for (int j = 0; j < 4; ++j) {
                if (p + 16 * j < K_DIM) {
#pragma unroll
                    for (int t = 0; t < CNT; ++t) {
                        acc[t][0] = __builtin_amdgcn_mfma_f32_16x16x32_f16(a0[j], ring[t + j], acc[t][0], 0, 0, 0);
                        acc[t][1] = __builtin_amdgcn_mfma_f32_16x16x32_f16(a1[j], ring[t + j], acc[t][1], 0, 0, 0);
                    }
                }
            }
        }
    }
#undef LDFRAG
}

// ---------------------------------------------------------------------------
// Fused kernel, tiered (r5-verified; EW stride 52 this round):
// ---------------------------------------------------------------------------
template <bool PRE_G, bool USE_EW>
__launch_bounds__(256, 4)
__global__ void fused_kernel(const int* __restrict__ x,
                             const int* __restrict__ mask,     // bool -> int32
                             const unsigned* __restrict__ Gpk,
                             const float* __restrict__ EW,
                             const float* __restrict__ emb,
                             const float* __restrict__ Lt,
                             const float* __restrict__ rnl,
                             const float* __restrict__ conv_b,
                             const float* __restrict__ w1,
                             const float* __restrict__ b1,
                             const float* __restrict__ w2,
                             const float* __restrict__ b2,
                             const short* __restrict__ wA,
                             float* __restrict__ out) {
    __shared__ __align__(16) char smem[GT_BYTES];   // gT, later aliased
    __shared__ unsigned short toks[S_DIM];

    short* gT   = (short*)smem;
    float* marr = (float*)(smem);            // [0,    800)   after conv
    float* red  = (float*)(smem + 1024);     // cross-wave scratch (8 floats)
    float* bw   = (float*)(smem + 2048);     // [2048, 2848)
    float* zp   = (float*)(smem + 3072);     // 4 x 100 (or 4 x 64)
    float* zsh  = (float*)(smem + 4672);
    float* hsh  = (float*)(smem + 5120);

    const int tid  = threadIdx.x;
    const int b    = blockIdx.x;
    const int lane = tid & 63;
    const int wv   = tid >> 6;
    const int n    = lane & 15;

    // ---- zero only the pad rows [0,25) and [225,250) ----
    {
        float4 z{0.f, 0.f, 0.f, 0.f};
        for (int i = tid; i < 50 * 8; i += 256) {
            const int rr  = i >> 3;
            const int row = (rr < 25) ? rr : rr + 200;
            ((float4*)(smem + row * GT_STRIDE))[i & 7] = z;
        }
    }

    const int s    = tid;
    const bool act = (s < S_DIM);
    int tok = 0, msk = 0;
    if (act) {
        tok = x[b * S_DIM + s];
        msk = mask[b * S_DIM + s];
        toks[s] = (unsigned short)tok;
    }
    __syncthreads();

    // ---- phase 1: packed g row -> swizzled LDS ----
    if (act) {
        const int row = PADW + s;
        const int h8  = row & 7;
        uint4* rw = (uint4*)(smem + row * GT_STRIDE);
        if (PRE_G) {
            const uint4* gp = (const uint4*)(Gpk + (size_t)tok * 32); // one 128B line
            uint4 t0 = gp[0], t1 = gp[1], t2 = gp[2], t3 = gp[3];
            uint4 t4 = gp[4], t5 = gp[5], t6 = gp[6], t7 = gp[7];
            rw[0 ^ h8] = t0; rw[1 ^ h8] = t1; rw[2 ^ h8] = t2; rw[3 ^ h8] = t3;
            rw[4 ^ h8] = t4; rw[5 ^ h8] = t5; rw[6 ^ h8] = t6; rw[7 ^ h8] = t7;
        } else {
            // verified r3 in-kernel cosine path
            f32x2 dacc2[10];
#pragma unroll
            for (int i = 0; i < 10; ++i) dacc2[i] = f32x2{0.f, 0.f};
            float n2 = 0.f;
            const float4* er  = (const float4*)(emb + (size_t)tok * E_DIM);
            const f32x2* Lt2 = (const f32x2*)Lt;
            for (int j = 0; j < 25; ++j) {
                const float4 r = er[j];
                n2 += r.x * r.x + r.y * r.y + r.z * r.z + r.w * r.w;
                const float rv[4] = {r.x, r.y, r.z, r.w};
#pragma unroll
                for (int u = 0; u < 4; ++u) {
                    const f32x2 xe = {rv[u], rv[u]};
                    const f32x2* Lrow = Lt2 + (j * 4 + u) * 10;
#pragma unroll
                    for (int i = 0; i < 10; ++i)
                        dacc2[i] += xe * Lrow[i];
                }
            }
            const float xn    = sqrtf(n2);
            const float rxn16 = (xn > 0.f) ? 16.f / xn : 0.f;

            unsigned short gh[C_DIM], gl[C_DIM];
#pragma unroll
            for (int c = 0; c < C_DIM; ++c) {
                float a = dacc2[c >> 1][c & 1] * rnl[c] * rxn16;
                _Float16 h = (_Float16)a;
                _Float16 l = (_Float16)(a - (float)h);
                __builtin_memcpy(&gh[c], &h, 2);
                __builtin_memcpy(&gl[c], &l, 2);
            }
#define PK(a, b) ((unsigned)(a) | ((unsigned)(b) << 16))
            unsigned tv[32];
#pragma unroll
            for (int d = 0; d < 10; ++d) tv[d] = PK(gh[2 * d], gh[2 * d + 1]);
#pragma unroll
            for (int d = 0; d < 6; ++d)  tv[10 + d] = PK(gh[2 * d], gh[2 * d + 1]);
#pragma unroll
            for (int d = 0; d < 4; ++d)  tv[16 + d] = PK(gh[12 + 2 * d], gh[13 + 2 * d]);
#pragma unroll
            for (int d = 0; d < 10; ++d) tv[20 + d] = PK(gl[2 * d], gl[2 * d + 1]);
            tv[30] = 0u; tv[31] = 0u;
#undef PK
#pragma unroll
            for (int g = 0; g < 8; ++g) {
                uint4 v;
                v.x = tv[4 * g + 0]; v.y = tv[4 * g + 1];
                v.z = tv[4 * g + 2]; v.w = tv[4 * g + 3];
                rw[g ^ h8] = v;
            }
        }
    }
    __syncthreads();

    // ---- conv: waves split the 13 n-tiles (4/3/3/3) ----
    f32x4 acc[4][2];
#pragma unroll
    for (int t = 0; t < 4; ++t) {
        acc[t][0] = f32x4{0.f, 0.f, 0.f, 0.f};
        acc[t][1] = f32x4{0.f, 0.f, 0.f, 0.f};
    }
    const int nt0 = (wv == 0) ? 0 : (1 + wv * 3);      // 0,4,7,10
    const int cnt = (wv == 0) ? 4 : 3;
    const char* rowbase = (const char*)gT + (nt0 * 16 + n) * GT_STRIDE;
    if (wv == 0) conv_tiles<4>(wA, rowbase, acc, lane);
    else         conv_tiles<3>(wA, rowbase, acc, lane);

    __syncthreads();   // gT dead; overlay becomes live

    // ---- epilogue: relu+bias+channel max -> marr[s] (static t indexing) ----
    {
        const int q = lane >> 4;
        const float inv = 1.f / 4096.f;
        float cb0[4], cb1[4];
#pragma unroll
        for (int r = 0; r < 4; ++r) {
            cb0[r] = conv_b[4 * q + r];
            cb1[r] = (q == 0) ? conv_b[16 + r] : 0.f;
        }
#pragma unroll
        for (int t = 0; t < 4; ++t) {
            if (t < cnt) {
                float m = 0.f;   // relu floor
#pragma unroll
                for (int r = 0; r < 4; ++r) m = fmaxf(m, acc[t][0][r] * inv + cb0[r]);
                if (q == 0) {
#pragma unroll
                    for (int r = 0; r < 4; ++r) m = fmaxf(m, acc[t][1][r] * inv + cb1[r]);
                }
                m = fmaxf(m, __shfl_xor(m, 16));
                m = fmaxf(m, __shfl_xor(m, 32));
                const int ss = (nt0 + t) * 16 + n;
                if (q == 0 && ss < S_DIM) marr[ss] = m;
            }
        }
    }
    __syncthreads();

    // ---- softmax over s: wave shuffles + 4-slot cross-wave ----
    {
        float mval = act ? ((msk != 0) ? marr[s] : -1e13f) : -1e30f;
        float lm = mval;
#pragma unroll
        for (int off = 32; off > 0; off >>= 1) lm = fmaxf(lm, __shfl_xor(lm, off));
        if (lane == 0) red[wv] = lm;
        __syncthreads();
        const float gmax = fmaxf(fmaxf(red[0], red[1]), fmaxf(red[2], red[3]));
        const float p = act ? expf(mval - gmax) : 0.f;
        float ps = p;
#pragma unroll
        for (int off = 32; off > 0; off >>= 1) ps += __shfl_xor(ps, off);
        if (lane == 0) red[4 + wv] = ps;
        __syncthreads();
        const float gsum = (red[4] + red[5]) + (red[6] + red[7]);
        if (act) bw[s] = p / gsum;
    }
    __syncthreads();

    if (USE_EW) {
        // ---- pooling in w1-space over EW rows (stride 52); MLP1 gone ----
        {
            const bool pu = (lane < E_DIM / 2);
            float za = 0.f, zb = 0.f;
            const int s0 = wv * 50;
            for (int ss = s0; ss < s0 + 50; ss += 2) {
                const float  w0  = bw[ss];
                const float  w1v = bw[ss + 1];
                const float* r0 = EW + (size_t)toks[ss] * 52;
                const float* r1 = EW + (size_t)toks[ss + 1] * 52;
                if (pu) {
                    za += w0  * r0[lane];
                    zb += w1v * r1[lane];
                }
            }
            if (pu) zp[wv * 64 + lane] = za + zb;
        }
        __syncthreads();
        if (tid < E_DIM / 2) {
            const float h = zp[tid] + zp[64 + tid] + zp[128 + tid] + zp[192 + tid] + b1[tid];
            hsh[tid] = fmaxf(h, 0.f);
        }
        __syncthreads();
    } else {
        // ---- r3 pooling over emb + MLP layer 1 ----
        {
            float za0 = 0.f, zb0 = 0.f, za1 = 0.f, zb1 = 0.f;
            const int s0 = wv * 50;
            for (int ss = s0; ss < s0 + 50; ss += 2) {
                const float  w0  = bw[ss];
                const float  w1v = bw[ss + 1];
                const float* r0 = emb + (size_t)toks[ss] * E_DIM;
                const float* r1 = emb + (size_t)toks[ss + 1] * E_DIM;
                za0 += w0 * r0[lane];
                za1 += w1v * r1[lane];
                if (lane < E_DIM - 64) {
                    zb0 += w0 * r0[64 + lane];
                    zb1 += w1v * r1[64 + lane];
                }
            }
            zp[wv * E_DIM + lane] = za0 + za1;
            if (lane < E_DIM - 64) zp[wv * E_DIM + 64 + lane] = zb0 + zb1;
        }
        __syncthreads();
        if (tid < E_DIM)
            zsh[tid] = zp[tid] + zp[E_DIM + tid] + zp[2 * E_DIM + tid] + zp[3 * E_DIM + tid];
        __syncthreads();
        if (tid < E_DIM / 2) {
            float h = b1[tid];
            for (int e = 0; e < E_DIM; ++e) h += zsh[e] * w1[e * (E_DIM / 2) + tid];
            hsh[tid] = fmaxf(h, 0.f);
        }
        __syncthreads();
    }

    if (tid < C_DIM) {
        float o = b2[tid];
#pragma unroll
        for (int j = 0; j < E_DIM / 2; ++j) o += hsh[j] * w2[j * C_DIM + tid];
        out[b * C_DIM + tid] = o;
    }
}

// ---------------------------------------------------------------------------
extern "C" void kernel_launch(void* const* d_in, const int* in_sizes, int n_in,
                              void* d_out, int out_size, void* d_ws, size_t ws_size,
                              hipStream_t stream) {
    const int*   x      = (const int*)d_in[0];
    const int*   mask   = (const int*)d_in[2];    // bool delivered as int32
    const float* emb    = (const float*)d_in[3];
    const float* labels = (const float*)d_in[4];
    const float* conv_w = (const float*)d_in[5];
    const float* conv_b = (const float*)d_in[6];
    const float* w1     = (const float*)d_in[7];
    const float* b1     = (const float*)d_in[8];
    const float* w2     = (const float*)d_in[9];
    const float* b2     = (const float*)d_in[10];
    float*       out    = (float*)d_out;

    short*    wA  = (short*)d_ws;                         // 208896 B
    short*    wAv = (short*)((char*)d_ws + OFF_WAV);      // 51200 B
    float*    Lt  = (float*)((char*)d_ws + OFF_LT);
    float*    rnl = (float*)((char*)d_ws + OFF_RNL);
    unsigned* Gpk = (unsigned*)((char*)d_ws + OFF_GP);
    float*    EW  = (float*)((char*)d_ws + OFF_EW);

    const int prep_n = NA_SHORTS + C_DIM * E_DIM + C_DIM + NV_SHORTS;
    prep_kernel<<<(prep_n + 255) / 256, 256, 0, stream>>>(conv_w, labels, w1,
                                                          wA, wAv, Lt, rnl);

    const int vg = (V_DIM + 63) / 64;
    if (ws_size >= NEED_FULL) {
        vocab_mfma<true><<<vg, 256, 0, stream>>>(emb, wAv, rnl, Gpk, EW);
        fused_kernel<true, true><<<B_DIM, 256, 0, stream>>>(
            x, mask, Gpk, EW, emb, Lt, rnl, conv_b, w1, b1, w2, b2, wA, out);
    } else if (ws_size >= NEED_G) {
        vocab_mfma<false><<<vg, 256, 0, stream>>>(emb, wAv, rnl, Gpk, EW);
        fused_kernel<true, false><<<B_DIM, 256, 0, stream>>>(
            x, mask, Gpk, EW, emb, Lt, rnl, conv_b, w1, b1, w2, b2, wA, out);
    } else {
        fused_kernel<false, false><<<B_DIM, 256, 0, stream>>>(
            x, mask, Gpk, EW, emb, Lt, rnl, conv_b, w1, b1, w2, b2, wA, out);
    }
}

// Round 9
// 266.314 us; speedup vs baseline: 1.0523x; 1.0379x over previous
//
#include <hip/hip_runtime.h>
#include <math.h>

#define B_DIM 4096
#define S_DIM 200
#define E_DIM 100
#define C_DIM 20
#define K_DIM 51
#define PADW  25
#define V_DIM 50000

typedef _Float16 f16x8 __attribute__((ext_vector_type(8)));
typedef float    f32x4 __attribute__((ext_vector_type(4)));
typedef float    f32x2 __attribute__((ext_vector_type(2)));

// gT: 128B rows (img0 64B | img1 64B), XOR-swizzled 16B groups by (row&7).
// 272 rows so the K-split ring (max row 270) never reads past the LDS
// allocation; rows >= 250 feed only discarded output columns (s' >= 200).
#define GT_STRIDE 128
#define GT_ROWS2  272
#define GT_BYTES  (GT_ROWS2 * GT_STRIDE)  // 34816
#define NA_FRAGS  (K_DIM*2*2)    // (k, img, mt)
#define NA_SHORTS (NA_FRAGS*512) // 104448

// workspace layout (bytes); tiers guarded by ws_size (r4 lesson).  r6 layout.
#define OFF_LT    208896u                 // 2000 floats
#define OFF_RNL   216896u                 // 20 floats
#define OFF_WC    216976u                 // 100x72 floats (28800 B)
#define OFF_GP    245776u                 // 50000 x 128B packed g rows (6.4 MB)
#define OFF_EW    6645776u                // 50000 x 256B (64-float rows, 12.8 MB)
#define NEED_G    6645776u
#define NEED_FULL 19445776u               // proven available (r5/r6 ran full)

// ---------------------------------------------------------------------------
// Prep (r6-verified): conv A-frags; Lt; rnl; Wc columns for vocab_kernel2.
// ---------------------------------------------------------------------------
__global__ void prep_kernel(const float* __restrict__ conv_w,
                            const float* __restrict__ labels,
                            const float* __restrict__ w1,
                            short* __restrict__ wA,
                            float* __restrict__ Lt,
                            float* __restrict__ rnl,
                            float* __restrict__ Wc) {
    int idx = blockIdx.x * 256 + threadIdx.x;
    if (idx < NA_SHORTS) {
        int frag = idx >> 9;           // ((k*2+img)*2+mt)
        int r    = idx & 511;
        int lane = r >> 3;
        int j    = r & 7;
        int mt   = frag & 1;
        int img  = (frag >> 1) & 1;
        int k    = frag >> 2;
        int o  = mt * 16 + (lane & 15);
        int kc = (lane >> 4) * 8 + j;  // K-col 0..31

        int i = -1, lo = 0;
        if (img == 0) {
            if (kc < 20) { i = kc;      lo = 0; }
            else         { i = kc - 20; lo = 1; }
        } else {
            if (kc < 8)       { i = 12 + kc; lo = 1; }
            else if (kc < 28) { i = kc - 8;  lo = 0; }
        }
        float v = 0.f;
        if (o < C_DIM && i >= 0) v = conv_w[(o * C_DIM + i) * K_DIM + k] * 256.f;
        _Float16 hi  = (_Float16)v;
        _Float16 val = lo ? (_Float16)(v - (float)hi) : hi;
        unsigned short bits;
        __builtin_memcpy(&bits, &val, 2);
        wA[idx] = (short)bits;
    } else if (idx < NA_SHORTS + C_DIM * E_DIM) {
        int t = idx - NA_SHORTS;
        int e = t / C_DIM, c = t % C_DIM;
        Lt[t] = labels[c * E_DIM + e];
    } else if (idx < NA_SHORTS + C_DIM * E_DIM + C_DIM) {
        int c = idx - NA_SHORTS - C_DIM * E_DIM;
        float s = 0.f;
        for (int e = 0; e < E_DIM; ++e) { float v = labels[c * E_DIM + e]; s += v * v; }
        float nn = sqrtf(s);
        rnl[c] = (nn > 0.f) ? 1.f / nn : 0.f;
    } else if (idx < NA_SHORTS + C_DIM * E_DIM + C_DIM + E_DIM * 72) {
        int t = idx - NA_SHORTS - C_DIM * E_DIM - C_DIM;
        int e = t / 72, o = t % 72;
        float v = 0.f;
        if (o < C_DIM)      v = labels[o * E_DIM + e];
        else if (o < 70)    v = w1[e * (E_DIM / 2) + (o - C_DIM)];
        Wc[t] = v;
    }
}

// ---------------------------------------------------------------------------
// Vocab precompute (r6-verified, VCH=24 output-parallel form; best total).
// ---------------------------------------------------------------------------
#define VCH 24
template <bool DO_EW>
__launch_bounds__(256, 2)
__global__ void vocab_kernel2(const float* __restrict__ emb,
                              const float* __restrict__ Wc,   // [100][72]
                              const float* __restrict__ rnl,
                              unsigned* __restrict__ Gpk,
                              float* __restrict__ EW) {
    __shared__ __align__(16) float embL[VCH][E_DIM];
    __shared__ float dL[VCH][C_DIM];
    __shared__ float n2L[VCH];
    __shared__ float rnlL[C_DIM];

    const int tid = threadIdx.x;
    const int v0  = blockIdx.x * VCH;

    if (tid < C_DIM) rnlL[tid] = rnl[tid];

    for (int i = tid; i < VCH * 25; i += 256) {
        const int r = i / 25, c4 = i % 25;
        const int v = v0 + r;
        float4 val{0.f, 0.f, 0.f, 0.f};
        if (v < V_DIM) val = ((const float4*)(emb + (size_t)v * E_DIM))[c4];
        ((float4*)&embL[r][0])[c4] = val;
    }
    __syncthreads();

    const int o    = tid % 72;
    const int roff = tid / 72;
    if (roff < 3) {
        f32x4 wcv[25];
#pragma unroll
        for (int eb = 0; eb < 25; ++eb) {
            f32x4 w;
            w[0] = Wc[(eb * 4 + 0) * 72 + o];
            w[1] = Wc[(eb * 4 + 1) * 72 + o];
            w[2] = Wc[(eb * 4 + 2) * 72 + o];
            w[3] = Wc[(eb * 4 + 3) * 72 + o];
            wcv[eb] = w;
        }
        for (int rr = roff; rr < VCH; rr += 3) {
            const int v = v0 + rr;
            const f32x4* er4 = (const f32x4*)&embL[rr][0];
            f32x4 a4{0.f, 0.f, 0.f, 0.f};
            if (o == 70) {
#pragma unroll
                for (int eb = 0; eb < 25; ++eb) { const f32x4 ev = er4[eb]; a4 += ev * ev; }
                n2L[rr] = a4[0] + a4[1] + a4[2] + a4[3];
            } else if (o < 70) {
#pragma unroll
                for (int eb = 0; eb < 25; ++eb) { const f32x4 ev = er4[eb]; a4 += ev * wcv[eb]; }
                const float acc = a4[0] + a4[1] + a4[2] + a4[3];
                if (o < C_DIM) dL[rr][o] = acc;
                else if (DO_EW && v < V_DIM) EW[(size_t)v * 64 + (o - C_DIM)] = acc;
            }
        }
    }
    __syncthreads();

    if (tid < VCH) {
        const int v = v0 + tid;
        if (v < V_DIM) {
            const float n2 = n2L[tid];
            const float xn = sqrtf(n2);
            const float rxn16 = (xn > 0.f) ? 16.f / xn : 0.f;
            unsigned short gh[C_DIM], gl[C_DIM];
#pragma unroll
            for (int c = 0; c < C_DIM; ++c) {
                float a = dL[tid][c] * rnlL[c] * rxn16;
                _Float16 h = (_Float16)a;
                _Float16 l = (_Float16)(a - (float)h);
                __builtin_memcpy(&gh[c], &h, 2);
                __builtin_memcpy(&gl[c], &l, 2);
            }
#define PK(a, b) ((unsigned)(a) | ((unsigned)(b) << 16))
            unsigned tv[32];
#pragma unroll
            for (int d = 0; d < 10; ++d) tv[d] = PK(gh[2 * d], gh[2 * d + 1]);
#pragma unroll
            for (int d = 0; d < 6; ++d)  tv[10 + d] = PK(gh[2 * d], gh[2 * d + 1]);
#pragma unroll
            for (int d = 0; d < 4; ++d)  tv[16 + d] = PK(gh[12 + 2 * d], gh[13 + 2 * d]);
#pragma unroll
            for (int d = 0; d < 10; ++d) tv[20 + d] = PK(gl[2 * d], gl[2 * d + 1]);
            tv[30] = 0u; tv[31] = 0u;
#undef PK
            uint4* go = (uint4*)(Gpk + (size_t)v * 32);
#pragma unroll
            for (int g = 0; g < 8; ++g) {
                uint4 q;
                q.x = tv[4 * g + 0]; q.y = tv[4 * g + 1];
                q.z = tv[4 * g + 2]; q.w = tv[4 * g + 3];
                go[g] = q;
            }
        }
    }
}

// ---------------------------------------------------------------------------
// K-split phase-ring conv (r9).  r8 accounting: all 4 waves re-reading the
// full 204KB frag set = 816KB/block of L2 traffic (~97us/CU) sits on the
// critical path next to the ~86us matrix floor.  Split K across wave pairs:
// this wave handles j in {J0, J0+1} (k = p+16j) for CNT tiles -> per-block
// frag traffic halves to 408KB.  Ring slot i holds row (p+16(J0+i)); MFMA
// (t, j-J0) uses slot t+(j-J0).  J0=2: j=3 valid iff p<3 (k=p+48<51).
// K-halves reduced via LDS partials after gT dies (r2-verified math; r3-safe
// static indexing everywhere).
// ---------------------------------------------------------------------------
template <int CNT, int J0>
__device__ __forceinline__ void conv_ksplit(const short* __restrict__ wA,
                                            const char* rowbase,   // gT + (tg*16+n)*GT_STRIDE
                                            f32x4 (&acc)[7][2],
                                            int lane) {
    const int n = lane & 15;
    const int q = lane >> 4;
#define LDFRAG(k, img, mt) (*(const f16x8*)(wA + (((k) * 2 + (img)) * 2 + (mt)) * 512 + lane * 8))
#pragma unroll
    for (int img = 0; img < 2; ++img) {
#pragma unroll 1
        for (int p = 0; p < 16; ++p) {
            const bool j1ok = (J0 == 0) || (p < 3);
            f16x8 a0[2], a1[2];
            a0[0] = LDFRAG(p + 16 * J0, img, 0);
            a1[0] = LDFRAG(p + 16 * J0, img, 1);
            if (j1ok) {
                a0[1] = LDFRAG(p + 16 * (J0 + 1), img, 0);
                a1[1] = LDFRAG(p + 16 * (J0 + 1), img, 1);
            }
            // swizzled row read; row&7 = (n+p)&7 (tg*16, 16*J0, 16*i all = 0 mod 8)
            const int off = (q * 16 + img * 64) ^ (((n + p) & 7) << 4);
            const char* rp = rowbase + (p + 16 * J0) * GT_STRIDE + off;
            f16x8 ring[CNT + 1];
#pragma unroll
            for (int i = 0; i <= CNT; ++i) {
                if (i < CNT || j1ok)
                    ring[i] = *(const f16x8*)(rp + i * 16 * GT_STRIDE);
            }
#pragma unroll
            for (int t = 0; t < CNT; ++t) {
                acc[t][0] = __builtin_amdgcn_mfma_f32_16x16x32_f16(a0[0], ring[t], acc[t][0], 0, 0, 0);
                acc[t][1] = __builtin_amdgcn_mfma_f32_16x16x32_f16(a1[0], ring[t], acc[t][1], 0, 0, 0);
            }
            if (j1ok) {
#pragma unroll
                for (int t = 0; t < CNT; ++t) {
                    acc[t][0] = __builtin_amdgcn_mfma_f32_16x16x32_f16(a0[1], ring[t + 1], acc[t][0], 0, 0, 0);
                    acc[t][1] = __builtin_amdgcn_mfma_f32_16x16x32_f16(a1[1], ring[t + 1], acc[t][1], 0, 0, 0);
                }
            }
        }
    }
#undef LDFRAG
}

// ---------------------------------------------------------------------------
// Fused kernel, tiered (r6-verified phases; conv now K-split):
//   wv0: tiles 0-6 j{0,1}   wv1: tiles 7-12 j{0,1}
//   wv2: tiles 0-6 j{2,3}   wv3: tiles 7-12 j{2,3}
// ---------------------------------------------------------------------------
template <bool PRE_G, bool USE_EW>
__launch_bounds__(256, 4)
__global__ void fused_kernel(const int* __restrict__ x,
                             const int* __restrict__ mask,     // bool -> int32
                             const unsigned* __restrict__ Gpk,
                             const float* __restrict__ EW,
                             const float* __restrict__ emb,
                             const float* __restrict__ Lt,
                             const float* __restrict__ rnl,
                             const float* __restrict__ conv_b,
                             const float* __restrict__ w1,
                             const float* __restrict__ b1,
                             const float* __restrict__ w2,
                             const float* __restrict__ b2,
                             const short* __restrict__ wA,
                             float* __restrict__ out) {
    __shared__ __align__(16) char smem[GT_BYTES];   // gT (272 rows), later aliased
    __shared__ unsigned short toks[S_DIM];

    short* gT   = (short*)smem;
    float* marr = (float*)(smem);            // [0,    800)   after conv
    float* red  = (float*)(smem + 1024);     // cross-wave scratch (8 floats)
    float* bw   = (float*)(smem + 2048);     // [2048, 2848)
    float* zp   = (float*)(smem + 3072);     // 4 x 64 (or 4 x 100 in fallback)
    float* part = (float*)(smem + 4096);     // K-half partials, 26624 B
                                             // (live only conv-end..epilogue)
    float* zsh  = (float*)(smem + 31744);
    float* hsh  = (float*)(smem + 32256);

    const int tid  = threadIdx.x;
    const int b    = blockIdx.x;
    const int lane = tid & 63;
    const int wv   = tid >> 6;
    const int n    = lane & 15;

    // ---- zero pad rows [0,25) and [225,250); rows 250-271 may hold garbage
    // but feed only discarded columns s' >= 200 (geometry: row = s' + k) ----
    {
        float4 z{0.f, 0.f, 0.f, 0.f};
        for (int i = tid; i < 50 * 8; i += 256) {
            const int rr  = i >> 3;
            const int row = (rr < 25) ? rr : rr + 200;
            ((float4*)(smem + row * GT_STRIDE))[i & 7] = z;
        }
    }

    const int s    = tid;
    const bool act = (s < S_DIM);
    int tok = 0, msk = 0;
    if (act) {
        tok = x[b * S_DIM + s];
        msk = mask[b * S_DIM + s];
        toks[s] = (unsigned short)tok;
    }
    __syncthreads();

    // ---- phase 1: packed g row -> swizzled LDS ----
    if (act) {
        const int row = PADW + s;
        const int h8  = row & 7;
        uint4* rw = (uint4*)(smem + row * GT_STRIDE);
        if (PRE_G) {
            const uint4* gp = (const uint4*)(Gpk + (size_t)tok * 32); // one 128B line
            uint4 t0 = gp[0], t1 = gp[1], t2 = gp[2], t3 = gp[3];
            uint4 t4 = gp[4], t5 = gp[5], t6 = gp[6], t7 = gp[7];
            rw[0 ^ h8] = t0; rw[1 ^ h8] = t1; rw[2 ^ h8] = t2; rw[3 ^ h8] = t3;
            rw[4 ^ h8] = t4; rw[5 ^ h8] = t5; rw[6 ^ h8] = t6; rw[7 ^ h8] = t7;
        } else {
            // verified r3 in-kernel cosine path
            f32x2 dacc2[10];
#pragma unroll
            for (int i = 0; i < 10; ++i) dacc2[i] = f32x2{0.f, 0.f};
            float n2 = 0.f;
            const float4* er  = (const float4*)(emb + (size_t)tok * E_DIM);
            const f32x2* Lt2 = (const f32x2*)Lt;
            for (int j = 0; j < 25; ++j) {
                const float4 r = er[j];
                n2 += r.x * r.x + r.y * r.y + r.z * r.z + r.w * r.w;
                const float rv[4] = {r.x, r.y, r.z, r.w};
#pragma unroll
                for (int u = 0; u < 4; ++u) {
                    const f32x2 xe = {rv[u], rv[u]};
                    const f32x2* Lrow = Lt2 + (j * 4 + u) * 10;
#pragma unroll
                    for (int i = 0; i < 10; ++i)
                        dacc2[i] += xe * Lrow[i];
                }
            }
            const float xn    = sqrtf(n2);
            const float rxn16 = (xn > 0.f) ? 16.f / xn : 0.f;

            unsigned short gh[C_DIM], gl[C_DIM];
#pragma unroll
            for (int c = 0; c < C_DIM; ++c) {
                float a = dacc2[c >> 1][c & 1] * rnl[c] * rxn16;
                _Float16 h = (_Float16)a;
                _Float16 l = (_Float16)(a - (float)h);
                __builtin_memcpy(&gh[c], &h, 2);
                __builtin_memcpy(&gl[c], &l, 2);
            }
#define PK(a, b) ((unsigned)(a) | ((unsigned)(b) << 16))
            unsigned tv[32];
#pragma unroll
            for (int d = 0; d < 10; ++d) tv[d] = PK(gh[2 * d], gh[2 * d + 1]);
#pragma unroll
            for (int d = 0; d < 6; ++d)  tv[10 + d] = PK(gh[2 * d], gh[2 * d + 1]);
#pragma unroll
            for (int d = 0; d < 4; ++d)  tv[16 + d] = PK(gh[12 + 2 * d], gh[13 + 2 * d]);
#pragma unroll
            for (int d = 0; d < 10; ++d) tv[20 + d] = PK(gl[2 * d], gl[2 * d + 1]);
            tv[30] = 0u; tv[31] = 0u;
#undef PK
#pragma unroll
            for (int g = 0; g < 8; ++g) {
                uint4 v;
                v.x = tv[4 * g + 0]; v.y = tv[4 * g + 1];
                v.z = tv[4 * g + 2]; v.w = tv[4 * g + 3];
                rw[g ^ h8] = v;
            }
        }
    }
    __syncthreads();

    // ---- conv: tile-half x K-half wave split ----
    f32x4 acc[7][2];
#pragma unroll
    for (int t = 0; t < 7; ++t) {
        acc[t][0] = f32x4{0.f, 0.f, 0.f, 0.f};
        acc[t][1] = f32x4{0.f, 0.f, 0.f, 0.f};
    }
    const int tg  = (wv & 1) ? 7 : 0;      // tile base (7 or 6 tiles)
    const int cnt = (wv & 1) ? 6 : 7;
    const char* rowbase = (const char*)gT + (tg * 16 + n) * GT_STRIDE;
    if      (wv == 0) conv_ksplit<7, 0>(wA, rowbase, acc, lane);
    else if (wv == 1) conv_ksplit<6, 0>(wA, rowbase, acc, lane);
    else if (wv == 2) conv_ksplit<7, 2>(wA, rowbase, acc, lane);
    else              conv_ksplit<6, 2>(wA, rowbase, acc, lane);

    __syncthreads();   // conv done; gT dead, part overlay becomes live

    // ---- K-half publish (waves 2,3) -- static t loop + runtime guard ----
    if (wv >= 2) {
#pragma unroll
        for (int t = 0; t < 7; ++t) {
            if (t < cnt) {
                *(f32x4*)(part + (((tg + t) * 2 + 0) * 64 + lane) * 4) = acc[t][0];
                *(f32x4*)(part + (((tg + t) * 2 + 1) * 64 + lane) * 4) = acc[t][1];
            }
        }
    }
    __syncthreads();

    // ---- epilogue (waves 0,1): add partials, relu+bias+channel max ----
    if (wv < 2) {
        const int q = lane >> 4;
        const float inv = 1.f / 4096.f;
        float cb0[4], cb1[4];
#pragma unroll
        for (int r = 0; r < 4; ++r) {
            cb0[r] = conv_b[4 * q + r];
            cb1[r] = (q == 0) ? conv_b[16 + r] : 0.f;
        }
#pragma unroll
        for (int t = 0; t < 7; ++t) {
            if (t < cnt) {
                const f32x4 p0 = *(const f32x4*)(part + (((tg + t) * 2 + 0) * 64 + lane) * 4);
                const f32x4 p1 = *(const f32x4*)(part + (((tg + t) * 2 + 1) * 64 + lane) * 4);
                const f32x4 s0 = acc[t][0] + p0;
                const f32x4 s1 = acc[t][1] + p1;
                float m = 0.f;   // relu floor
#pragma unroll
                for (int r = 0; r < 4; ++r) m = fmaxf(m, s0[r] * inv + cb0[r]);
                if (q == 0) {
#pragma unroll
                    for (int r = 0; r < 4; ++r) m = fmaxf(m, s1[r] * inv + cb1[r]);
                }
                m = fmaxf(m, __shfl_xor(m, 16));
                m = fmaxf(m, __shfl_xor(m, 32));
                const int ss = (tg + t) * 16 + n;
                if (q == 0 && ss < S_DIM) marr[ss] = m;
            }
        }
    }
    __syncthreads();

    // ---- softmax over s: wave shuffles + 4-slot cross-wave ----
    {
        float mval = act ? ((msk != 0) ? marr[s] : -1e13f) : -1e30f;
        float lm = mval;
#pragma unroll
        for (int off = 32; off > 0; off >>= 1) lm = fmaxf(lm, __shfl_xor(lm, off));
        if (lane == 0) red[wv] = lm;
        __syncthreads();
        const float gmax = fmaxf(fmaxf(red[0], red[1]), fmaxf(red[2], red[3]));
        const float p = act ? expf(mval - gmax) : 0.f;
        float ps = p;
#pragma unroll
        for (int off = 32; off > 0; off >>= 1) ps += __shfl_xor(ps, off);
        if (lane == 0) red[4 + wv] = ps;
        __syncthreads();
        const float gsum = (red[4] + red[5]) + (red[6] + red[7]);
        if (act) bw[s] = p / gsum;
    }
    __syncthreads();

    if (USE_EW) {
        // ---- pooling in w1-space over EW rows (stride 64); MLP1 gone ----
        {
            const bool pu = (lane < E_DIM / 2);
            float za = 0.f, zb = 0.f;
            const int s0 = wv * 50;
            for (int ss = s0; ss < s0 + 50; ss += 2) {
                const float  w0  = bw[ss];
                const float  w1v = bw[ss + 1];
                const float* r0 = EW + (size_t)toks[ss] * 64;
                const float* r1 = EW + (size_t)toks[ss + 1] * 64;
                if (pu) {
                    za += w0  * r0[lane];
                    zb += w1v * r1[lane];
                }
            }
            if (pu) zp[wv * 64 + lane] = za + zb;
        }
        __syncthreads();
        if (tid < E_DIM / 2) {
            const float h = zp[tid] + zp[64 + tid] + zp[128 + tid] + zp[192 + tid] + b1[tid];
            hsh[tid] = fmaxf(h, 0.f);
        }
        __syncthreads();
    } else {
        // ---- r3 pooling over emb + MLP layer 1 ----
        {
            float za0 = 0.f, zb0 = 0.f, za1 = 0.f, zb1 = 0.f;
            const int s0 = wv * 50;
            for (int ss = s0; ss < s0 + 50; ss += 2) {
                const float  w0  = bw[ss];
                const float  w1v = bw[ss + 1];
                const float* r0 = emb + (size_t)toks[ss] * E_DIM;
                const float* r1 = emb + (size_t)toks[ss + 1] * E_DIM;
                za0 += w0 * r0[lane];
                za1 += w1v * r1[lane];
                if (lane < E_DIM - 64) {
                    zb0 += w0 * r0[64 + lane];
                    zb1 += w1v * r1[64 + lane];
                }
            }
            zp[wv * E_DIM + lane] = za0 + za1;
            if (lane < E_DIM - 64) zp[wv * E_DIM + 64 + lane] = zb0 + zb1;
        }
        __syncthreads();
        if (tid < E_DIM)
            zsh[tid] = zp[tid] + zp[E_DIM + tid] + zp[2 * E_DIM + tid] + zp[3 * E_DIM + tid];
        __syncthreads();
        if (tid < E_DIM / 2) {
            float h = b1[tid];
            for (int e = 0; e < E_DIM; ++e) h += zsh[e] * w1[e * (E_DIM / 2) + tid];
            hsh[tid] = fmaxf(h, 0.f);
        }
        __syncthreads();
    }

    if (tid < C_DIM) {
        float o = b2[tid];
#pragma unroll
        for (int j = 0; j < E_DIM / 2; ++j) o += hsh[j] * w2[j * C_DIM + tid];
        out[b * C_DIM + tid] = o;
    }
}

// ---------------------------------------------------------------------------
extern "C" void kernel_launch(void* const* d_in, const int* in_sizes, int n_in,
                              void* d_out, int out_size, void* d_ws, size_t ws_size,
                              hipStream_t stream) {
    const int*   x      = (const int*)d_in[0];
    const int*   mask   = (const int*)d_in[2];    // bool delivered as int32
    const float* emb    = (const float*)d_in[3];
    const float* labels = (const float*)d_in[4];
    const float* conv_w = (const float*)d_in[5];
    const float* conv_b = (const float*)d_in[6];
    const float* w1     = (const float*)d_in[7];
    const float* b1     = (const float*)d_in[8];
    const float* w2     = (const float*)d_in[9];
    const float* b2     = (const float*)d_in[10];
    float*       out    = (float*)d_out;

    short*    wA  = (short*)d_ws;                         // 208896 B
    float*    Lt  = (float*)((char*)d_ws + OFF_LT);
    float*    rnl = (float*)((char*)d_ws + OFF_RNL);
    float*    Wc  = (float*)((char*)d_ws + OFF_WC);
    unsigned* Gpk = (unsigned*)((char*)d_ws + OFF_GP);
    float*    EW  = (float*)((char*)d_ws + OFF_EW);

    const int prep_n = NA_SHORTS + C_DIM * E_DIM + C_DIM + E_DIM * 72;
    prep_kernel<<<(prep_n + 255) / 256, 256, 0, stream>>>(conv_w, labels, w1,
                                                          wA, Lt, rnl, Wc);

    const int vg = (V_DIM + VCH - 1) / VCH;
    if (ws_size >= NEED_FULL) {
        vocab_kernel2<true><<<vg, 256, 0, stream>>>(emb, Wc, rnl, Gpk, EW);
        fused_kernel<true, true><<<B_DIM, 256, 0, stream>>>(
            x, mask, Gpk, EW, emb, Lt, rnl, conv_b, w1, b1, w2, b2, wA, out);
    } else if (ws_size >= NEED_G) {
        vocab_kernel2<false><<<vg, 256, 0, stream>>>(emb, Wc, rnl, Gpk, EW);
        fused_kernel<true, false><<<B_DIM, 256, 0, stream>>>(
            x, mask, Gpk, EW, emb, Lt, rnl, conv_b, w1, b1, w2, b2, wA, out);
    } else {
        fused_kernel<false, false><<<B_DIM, 256, 0, stream>>>(
            x, mask, Gpk, EW, emb, Lt, rnl, conv_b, w1, b1, w2, b2, wA, out);
    }
}

// Round 10
// 264.802 us; speedup vs baseline: 1.0583x; 1.0057x over previous
//
#include <hip/hip_runtime.h>
#include <math.h>

#define B_DIM 4096
#define S_DIM 200
#define E_DIM 100
#define C_DIM 20
#define K_DIM 51
#define PADW  25
#define V_DIM 50000

typedef _Float16 f16x8 __attribute__((ext_vector_type(8)));
typedef float    f32x4 __attribute__((ext_vector_type(4)));
typedef float    f32x2 __attribute__((ext_vector_type(2)));

// gT: 128B rows (img0 64B | img1 64B), XOR-swizzled 16B groups by (row&7).
// 272 rows so the K-split ring (max row 270) never reads past the LDS
// allocation; rows >= 250 feed only discarded output columns (s' >= 200).
#define GT_STRIDE 128
#define GT_ROWS2  272
#define GT_BYTES  (GT_ROWS2 * GT_STRIDE)  // 34816
#define NA_FRAGS  (K_DIM*2*2)    // (k, img, mt)
#define NA_SHORTS (NA_FRAGS*512) // 104448

// workspace layout (bytes); tiers guarded by ws_size (r4 lesson).  r6 layout.
#define OFF_LT    208896u                 // 2000 floats
#define OFF_RNL   216896u                 // 20 floats
#define OFF_WC    216976u                 // 100x72 floats (28800 B)
#define OFF_GP    245776u                 // 50000 x 128B packed g rows (6.4 MB)
#define OFF_EW    6645776u                // 50000 x 256B (64-float rows, 12.8 MB)
#define NEED_G    6645776u
#define NEED_FULL 19445776u               // proven available (r5/r6/r9 ran full)

// ---------------------------------------------------------------------------
// Prep (r6-verified): conv A-frags; Lt; rnl; Wc columns for vocab_kernel2.
// ---------------------------------------------------------------------------
__global__ void prep_kernel(const float* __restrict__ conv_w,
                            const float* __restrict__ labels,
                            const float* __restrict__ w1,
                            short* __restrict__ wA,
                            float* __restrict__ Lt,
                            float* __restrict__ rnl,
                            float* __restrict__ Wc) {
    int idx = blockIdx.x * 256 + threadIdx.x;
    if (idx < NA_SHORTS) {
        int frag = idx >> 9;           // ((k*2+img)*2+mt)
        int r    = idx & 511;
        int lane = r >> 3;
        int j    = r & 7;
        int mt   = frag & 1;
        int img  = (frag >> 1) & 1;
        int k    = frag >> 2;
        int o  = mt * 16 + (lane & 15);
        int kc = (lane >> 4) * 8 + j;  // K-col 0..31

        int i = -1, lo = 0;
        if (img == 0) {
            if (kc < 20) { i = kc;      lo = 0; }
            else         { i = kc - 20; lo = 1; }
        } else {
            if (kc < 8)       { i = 12 + kc; lo = 1; }
            else if (kc < 28) { i = kc - 8;  lo = 0; }
        }
        float v = 0.f;
        if (o < C_DIM && i >= 0) v = conv_w[(o * C_DIM + i) * K_DIM + k] * 256.f;
        _Float16 hi  = (_Float16)v;
        _Float16 val = lo ? (_Float16)(v - (float)hi) : hi;
        unsigned short bits;
        __builtin_memcpy(&bits, &val, 2);
        wA[idx] = (short)bits;
    } else if (idx < NA_SHORTS + C_DIM * E_DIM) {
        int t = idx - NA_SHORTS;
        int e = t / C_DIM, c = t % C_DIM;
        Lt[t] = labels[c * E_DIM + e];
    } else if (idx < NA_SHORTS + C_DIM * E_DIM + C_DIM) {
        int c = idx - NA_SHORTS - C_DIM * E_DIM;
        float s = 0.f;
        for (int e = 0; e < E_DIM; ++e) { float v = labels[c * E_DIM + e]; s += v * v; }
        float nn = sqrtf(s);
        rnl[c] = (nn > 0.f) ? 1.f / nn : 0.f;
    } else if (idx < NA_SHORTS + C_DIM * E_DIM + C_DIM + E_DIM * 72) {
        int t = idx - NA_SHORTS - C_DIM * E_DIM - C_DIM;
        int e = t / 72, o = t % 72;
        float v = 0.f;
        if (o < C_DIM)      v = labels[o * E_DIM + e];
        else if (o < 70)    v = w1[e * (E_DIM / 2) + (o - C_DIM)];
        Wc[t] = v;
    }
}

// ---------------------------------------------------------------------------
// Vocab precompute (r6-verified, VCH=24 output-parallel form; best total).
// ---------------------------------------------------------------------------
#define VCH 24
template <bool DO_EW>
__launch_bounds__(256, 2)
__global__ void vocab_kernel2(const float* __restrict__ emb,
                              const float* __restrict__ Wc,   // [100][72]
                              const float* __restrict__ rnl,
                              unsigned* __restrict__ Gpk,
                              float* __restrict__ EW) {
    __shared__ __align__(16) float embL[VCH][E_DIM];
    __shared__ float dL[VCH][C_DIM];
    __shared__ float n2L[VCH];
    __shared__ float rnlL[C_DIM];

    const int tid = threadIdx.x;
    const int v0  = blockIdx.x * VCH;

    if (tid < C_DIM) rnlL[tid] = rnl[tid];

    for (int i = tid; i < VCH * 25; i += 256) {
        const int r = i / 25, c4 = i % 25;
        const int v = v0 + r;
        float4 val{0.f, 0.f, 0.f, 0.f};
        if (v < V_DIM) val = ((const float4*)(emb + (size_t)v * E_DIM))[c4];
        ((float4*)&embL[r][0])[c4] = val;
    }
    __syncthreads();

    const int o    = tid % 72;
    const int roff = tid / 72;
    if (roff < 3) {
        f32x4 wcv[25];
#pragma unroll
        for (int eb = 0; eb < 25; ++eb) {
            f32x4 w;
            w[0] = Wc[(eb * 4 + 0) * 72 + o];
            w[1] = Wc[(eb * 4 + 1) * 72 + o];
            w[2] = Wc[(eb * 4 + 2) * 72 + o];
            w[3] = Wc[(eb * 4 + 3) * 72 + o];
            wcv[eb] = w;
        }
        for (int rr = roff; rr < VCH; rr += 3) {
            const int v = v0 + rr;
            const f32x4* er4 = (const f32x4*)&embL[rr][0];
            f32x4 a4{0.f, 0.f, 0.f, 0.f};
            if (o == 70) {
#pragma unroll
                for (int eb = 0; eb < 25; ++eb) { const f32x4 ev = er4[eb]; a4 += ev * ev; }
                n2L[rr] = a4[0] + a4[1] + a4[2] + a4[3];
            } else if (o < 70) {
#pragma unroll
                for (int eb = 0; eb < 25; ++eb) { const f32x4 ev = er4[eb]; a4 += ev * wcv[eb]; }
                const float acc = a4[0] + a4[1] + a4[2] + a4[3];
                if (o < C_DIM) dL[rr][o] = acc;
                else if (DO_EW && v < V_DIM) EW[(size_t)v * 64 + (o - C_DIM)] = acc;
            }
        }
    }
    __syncthreads();

    if (tid < VCH) {
        const int v = v0 + tid;
        if (v < V_DIM) {
            const float n2 = n2L[tid];
            const float xn = sqrtf(n2);
            const float rxn16 = (xn > 0.f) ? 16.f / xn : 0.f;
            unsigned short gh[C_DIM], gl[C_DIM];
#pragma unroll
            for (int c = 0; c < C_DIM; ++c) {
                float a = dL[tid][c] * rnlL[c] * rxn16;
                _Float16 h = (_Float16)a;
                _Float16 l = (_Float16)(a - (float)h);
                __builtin_memcpy(&gh[c], &h, 2);
                __builtin_memcpy(&gl[c], &l, 2);
            }
#define PK(a, b) ((unsigned)(a) | ((unsigned)(b) << 16))
            unsigned tv[32];
#pragma unroll
            for (int d = 0; d < 10; ++d) tv[d] = PK(gh[2 * d], gh[2 * d + 1]);
#pragma unroll
            for (int d = 0; d < 6; ++d)  tv[10 + d] = PK(gh[2 * d], gh[2 * d + 1]);
#pragma unroll
            for (int d = 0; d < 4; ++d)  tv[16 + d] = PK(gh[12 + 2 * d], gh[13 + 2 * d]);
#pragma unroll
            for (int d = 0; d < 10; ++d) tv[20 + d] = PK(gl[2 * d], gl[2 * d + 1]);
            tv[30] = 0u; tv[31] = 0u;
#undef PK
            uint4* go = (uint4*)(Gpk + (size_t)v * 32);
#pragma unroll
            for (int g = 0; g < 8; ++g) {
                uint4 q;
                q.x = tv[4 * g + 0]; q.y = tv[4 * g + 1];
                q.z = tv[4 * g + 2]; q.w = tv[4 * g + 3];
                go[g] = q;
            }
        }
    }
}

// ---------------------------------------------------------------------------
// K-split phase-ring conv (r9-verified) + T5 setprio around the MFMA
// clusters: the 4 waves have distinct roles (CNT/J0 differ), so the CU
// scheduler can favor MFMA-issuing waves (m191 regime, not m190 lockstep).
// ---------------------------------------------------------------------------
template <int CNT, int J0>
__device__ __forceinline__ void conv_ksplit(const short* __restrict__ wA,
                                            const char* rowbase,   // gT + (tg*16+n)*GT_STRIDE
                                            f32x4 (&acc)[7][2],
                                            int lane) {
    const int n = lane & 15;
    const int q = lane >> 4;
#define LDFRAG(k, img, mt) (*(const f16x8*)(wA + (((k) * 2 + (img)) * 2 + (mt)) * 512 + lane * 8))
#pragma unroll
    for (int img = 0; img < 2; ++img) {
#pragma unroll 1
        for (int p = 0; p < 16; ++p) {
            const bool j1ok = (J0 == 0) || (p < 3);
            f16x8 a0[2], a1[2];
            a0[0] = LDFRAG(p + 16 * J0, img, 0);
            a1[0] = LDFRAG(p + 16 * J0, img, 1);
            if (j1ok) {
                a0[1] = LDFRAG(p + 16 * (J0 + 1), img, 0);
                a1[1] = LDFRAG(p + 16 * (J0 + 1), img, 1);
            }
            // swizzled row read; row&7 = (n+p)&7 (tg*16, 16*J0, 16*i all = 0 mod 8)
            const int off = (q * 16 + img * 64) ^ (((n + p) & 7) << 4);
            const char* rp = rowbase + (p + 16 * J0) * GT_STRIDE + off;
            f16x8 ring[CNT + 1];
#pragma unroll
            for (int i = 0; i <= CNT; ++i) {
                if (i < CNT || j1ok)
                    ring[i] = *(const f16x8*)(rp + i * 16 * GT_STRIDE);
            }
            __builtin_amdgcn_s_setprio(1);
#pragma unroll
            for (int t = 0; t < CNT; ++t) {
                acc[t][0] = __builtin_amdgcn_mfma_f32_16x16x32_f16(a0[0], ring[t], acc[t][0], 0, 0, 0);
                acc[t][1] = __builtin_amdgcn_mfma_f32_16x16x32_f16(a1[0], ring[t], acc[t][1], 0, 0, 0);
            }
            if (j1ok) {
#pragma unroll
                for (int t = 0; t < CNT; ++t) {
                    acc[t][0] = __builtin_amdgcn_mfma_f32_16x16x32_f16(a0[1], ring[t + 1], acc[t][0], 0, 0, 0);
                    acc[t][1] = __builtin_amdgcn_mfma_f32_16x16x32_f16(a1[1], ring[t + 1], acc[t][1], 0, 0, 0);
                }
            }
            __builtin_amdgcn_s_setprio(0);
        }
    }
#undef LDFRAG
}

// ---------------------------------------------------------------------------
// Fused kernel, tiered (r9-verified phases; pooling now 4-chain unrolled):
//   wv0: tiles 0-6 j{0,1}   wv1: tiles 7-12 j{0,1}
//   wv2: tiles 0-6 j{2,3}   wv3: tiles 7-12 j{2,3}
// ---------------------------------------------------------------------------
template <bool PRE_G, bool USE_EW>
__launch_bounds__(256, 4)
__global__ void fused_kernel(const int* __restrict__ x,
                             const int* __restrict__ mask,     // bool -> int32
                             const unsigned* __restrict__ Gpk,
                             const float* __restrict__ EW,
                             const float* __restrict__ emb,
                             const float* __restrict__ Lt,
                             const float* __restrict__ rnl,
                             const float* __restrict__ conv_b,
                             const float* __restrict__ w1,
                             const float* __restrict__ b1,
                             const float* __restrict__ w2,
                             const float* __restrict__ b2,
                             const short* __restrict__ wA,
                             float* __restrict__ out) {
    __shared__ __align__(16) char smem[GT_BYTES];   // gT (272 rows), later aliased
    __shared__ unsigned short toks[S_DIM];

    short* gT   = (short*)smem;
    float* marr = (float*)(smem);            // [0,    800)   after conv
    float* red  = (float*)(smem + 1024);     // cross-wave scratch (8 floats)
    float* bw   = (float*)(smem + 2048);     // [2048, 2848)
    float* zp   = (float*)(smem + 3072);     // 4 x 64 (or 4 x 100 in fallback)
    float* part = (float*)(smem + 4096);     // K-half partials, 26624 B
                                             // (live only conv-end..epilogue)
    float* zsh  = (float*)(smem + 31744);
    float* hsh  = (float*)(smem + 32256);

    const int tid  = threadIdx.x;
    const int b    = blockIdx.x;
    const int lane = tid & 63;
    const int wv   = tid >> 6;
    const int n    = lane & 15;

    // ---- zero pad rows [0,25) and [225,250); rows 250-271 may hold garbage
    // but feed only discarded columns s' >= 200 (geometry: row = s' + k) ----
    {
        float4 z{0.f, 0.f, 0.f, 0.f};
        for (int i = tid; i < 50 * 8; i += 256) {
            const int rr  = i >> 3;
            const int row = (rr < 25) ? rr : rr + 200;
            ((float4*)(smem + row * GT_STRIDE))[i & 7] = z;
        }
    }

    const int s    = tid;
    const bool act = (s < S_DIM);
    int tok = 0, msk = 0;
    if (act) {
        tok = x[b * S_DIM + s];
        msk = mask[b * S_DIM + s];
        toks[s] = (unsigned short)tok;
    }
    __syncthreads();

    // ---- phase 1: packed g row -> swizzled LDS ----
    if (act) {
        const int row = PADW + s;
        const int h8  = row & 7;
        uint4* rw = (uint4*)(smem + row * GT_STRIDE);
        if (PRE_G) {
            const uint4* gp = (const uint4*)(Gpk + (size_t)tok * 32); // one 128B line
            uint4 t0 = gp[0], t1 = gp[1], t2 = gp[2], t3 = gp[3];
            uint4 t4 = gp[4], t5 = gp[5], t6 = gp[6], t7 = gp[7];
            rw[0 ^ h8] = t0; rw[1 ^ h8] = t1; rw[2 ^ h8] = t2; rw[3 ^ h8] = t3;
            rw[4 ^ h8] = t4; rw[5 ^ h8] = t5; rw[6 ^ h8] = t6; rw[7 ^ h8] = t7;
        } else {
            // verified r3 in-kernel cosine path
            f32x2 dacc2[10];
#pragma unroll
            for (int i = 0; i < 10; ++i) dacc2[i] = f32x2{0.f, 0.f};
            float n2 = 0.f;
            const float4* er  = (const float4*)(emb + (size_t)tok * E_DIM);
            const f32x2* Lt2 = (const f32x2*)Lt;
            for (int j = 0; j < 25; ++j) {
                const float4 r = er[j];
                n2 += r.x * r.x + r.y * r.y + r.z * r.z + r.w * r.w;
                const float rv[4] = {r.x, r.y, r.z, r.w};
#pragma unroll
                for (int u = 0; u < 4; ++u) {
                    const f32x2 xe = {rv[u], rv[u]};
                    const f32x2* Lrow = Lt2 + (j * 4 + u) * 10;
#pragma unroll
                    for (int i = 0; i < 10; ++i)
                        dacc2[i] += xe * Lrow[i];
                }
            }
            const float xn    = sqrtf(n2);
            const float rxn16 = (xn > 0.f) ? 16.f / xn : 0.f;

            unsigned short gh[C_DIM], gl[C_DIM];
#pragma unroll
            for (int c = 0; c < C_DIM; ++c) {
                float a = dacc2[c >> 1][c & 1] * rnl[c] * rxn16;
                _Float16 h = (_Float16)a;
                _Float16 l = (_Float16)(a - (float)h);
                __builtin_memcpy(&gh[c], &h, 2);
                __builtin_memcpy(&gl[c], &l, 2);
            }
#define PK(a, b) ((unsigned)(a) | ((unsigned)(b) << 16))
            unsigned tv[32];
#pragma unroll
            for (int d = 0; d < 10; ++d) tv[d] = PK(gh[2 * d], gh[2 * d + 1]);
#pragma unroll
            for (int d = 0; d < 6; ++d)  tv[10 + d] = PK(gh[2 * d], gh[2 * d + 1]);
#pragma unroll
            for (int d = 0; d < 4; ++d)  tv[16 + d] = PK(gh[12 + 2 * d], gh[13 + 2 * d]);
#pragma unroll
            for (int d = 0; d < 10; ++d) tv[20 + d] = PK(gl[2 * d], gl[2 * d + 1]);
            tv[30] = 0u; tv[31] = 0u;
#undef PK
#pragma unroll
            for (int g = 0; g < 8; ++g) {
                uint4 v;
                v.x = tv[4 * g + 0]; v.y = tv[4 * g + 1];
                v.z = tv[4 * g + 2]; v.w = tv[4 * g + 3];
                rw[g ^ h8] = v;
            }
        }
    }
    __syncthreads();

    // ---- conv: tile-half x K-half wave split ----
    f32x4 acc[7][2];
#pragma unroll
    for (int t = 0; t < 7; ++t) {
        acc[t][0] = f32x4{0.f, 0.f, 0.f, 0.f};
        acc[t][1] = f32x4{0.f, 0.f, 0.f, 0.f};
    }
    const int tg  = (wv & 1) ? 7 : 0;      // tile base (7 or 6 tiles)
    const int cnt = (wv & 1) ? 6 : 7;
    const char* rowbase = (const char*)gT + (tg * 16 + n) * GT_STRIDE;
    if      (wv == 0) conv_ksplit<7, 0>(wA, rowbase, acc, lane);
    else if (wv == 1) conv_ksplit<6, 0>(wA, rowbase, acc, lane);
    else if (wv == 2) conv_ksplit<7, 2>(wA, rowbase, acc, lane);
    else              conv_ksplit<6, 2>(wA, rowbase, acc, lane);

    __syncthreads();   // conv done; gT dead, part overlay becomes live

    // ---- K-half publish (waves 2,3) -- static t loop + runtime guard ----
    if (wv >= 2) {
#pragma unroll
        for (int t = 0; t < 7; ++t) {
            if (t < cnt) {
                *(f32x4*)(part + (((tg + t) * 2 + 0) * 64 + lane) * 4) = acc[t][0];
                *(f32x4*)(part + (((tg + t) * 2 + 1) * 64 + lane) * 4) = acc[t][1];
            }
        }
    }
    __syncthreads();

    // ---- epilogue (waves 0,1): add partials, relu+bias+channel max ----
    if (wv < 2) {
        const int q = lane >> 4;
        const float inv = 1.f / 4096.f;
        float cb0[4], cb1[4];
#pragma unroll
        for (int r = 0; r < 4; ++r) {
            cb0[r] = conv_b[4 * q + r];
            cb1[r] = (q == 0) ? conv_b[16 + r] : 0.f;
        }
#pragma unroll
        for (int t = 0; t < 7; ++t) {
            if (t < cnt) {
                const f32x4 p0 = *(const f32x4*)(part + (((tg + t) * 2 + 0) * 64 + lane) * 4);
                const f32x4 p1 = *(const f32x4*)(part + (((tg + t) * 2 + 1) * 64 + lane) * 4);
                const f32x4 s0 = acc[t][0] + p0;
                const f32x4 s1 = acc[t][1] + p1;
                float m = 0.f;   // relu floor
#pragma unroll
                for (int r = 0; r < 4; ++r) m = fmaxf(m, s0[r] * inv + cb0[r]);
                if (q == 0) {
#pragma unroll
                    for (int r = 0; r < 4; ++r) m = fmaxf(m, s1[r] * inv + cb1[r]);
                }
                m = fmaxf(m, __shfl_xor(m, 16));
                m = fmaxf(m, __shfl_xor(m, 32));
                const int ss = (tg + t) * 16 + n;
                if (q == 0 && ss < S_DIM) marr[ss] = m;
            }
        }
    }
    __syncthreads();

    // ---- softmax over s: wave shuffles + 4-slot cross-wave ----
    {
        float mval = act ? ((msk != 0) ? marr[s] : -1e13f) : -1e30f;
        float lm = mval;
#pragma unroll
        for (int off = 32; off > 0; off >>= 1) lm = fmaxf(lm, __shfl_xor(lm, off));
        if (lane == 0) red[wv] = lm;
        __syncthreads();
        const float gmax = fmaxf(fmaxf(red[0], red[1]), fmaxf(red[2], red[3]));
        const float p = act ? expf(mval - gmax) : 0.f;
        float ps = p;
#pragma unroll
        for (int off = 32; off > 0; off >>= 1) ps += __shfl_xor(ps, off);
        if (lane == 0) red[4 + wv] = ps;
        __syncthreads();
        const float gsum = (red[4] + red[5]) + (red[6] + red[7]);
        if (act) bw[s] = p / gsum;
    }
    __syncthreads();

    if (USE_EW) {
        // ---- pooling in w1-space over EW rows (stride 64); MLP1 gone.
        // 4 independent gather chains (r9 tail was latency-bound at 2). ----
        {
            const bool pu = (lane < E_DIM / 2);
            float za = 0.f, zb = 0.f, zc = 0.f, zd = 0.f;
            const int s0 = wv * 50;
#pragma unroll 1
            for (int g = 0; g < 12; ++g) {
                const int ss = s0 + g * 4;
                const float  w0 = bw[ss];
                const float  w1v = bw[ss + 1];
                const float  w2v = bw[ss + 2];
                const float  w3v = bw[ss + 3];
                const float* r0 = EW + (size_t)toks[ss] * 64;
                const float* r1 = EW + (size_t)toks[ss + 1] * 64;
                const float* r2 = EW + (size_t)toks[ss + 2] * 64;
                const float* r3 = EW + (size_t)toks[ss + 3] * 64;
                if (pu) {
                    za += w0  * r0[lane];
                    zb += w1v * r1[lane];
                    zc += w2v * r2[lane];
                    zd += w3v * r3[lane];
                }
            }
            {   // remainder pair (50 = 4*12 + 2)
                const int ss = s0 + 48;
                const float  w0 = bw[ss];
                const float  w1v = bw[ss + 1];
                const float* r0 = EW + (size_t)toks[ss] * 64;
                const float* r1 = EW + (size_t)toks[ss + 1] * 64;
                if (pu) {
                    za += w0  * r0[lane];
                    zb += w1v * r1[lane];
                }
            }
            if (pu) zp[wv * 64 + lane] = (za + zb) + (zc + zd);
        }
        __syncthreads();
        if (tid < E_DIM / 2) {
            const float h = zp[tid] + zp[64 + tid] + zp[128 + tid] + zp[192 + tid] + b1[tid];
            hsh[tid] = fmaxf(h, 0.f);
        }
        __syncthreads();
    } else {
        // ---- r3 pooling over emb + MLP layer 1 ----
        {
            float za0 = 0.f, zb0 = 0.f, za1 = 0.f, zb1 = 0.f;
            const int s0 = wv * 50;
            for (int ss = s0; ss < s0 + 50; ss += 2) {
                const float  w0  = bw[ss];
                const float  w1v = bw[ss + 1];
                const float* r0 = emb + (size_t)toks[ss] * E_DIM;
                const float* r1 = emb + (size_t)toks[ss + 1] * E_DIM;
                za0 += w0 * r0[lane];
                za1 += w1v * r1[lane];
                if (lane < E_DIM - 64) {
                    zb0 += w0 * r0[64 + lane];
                    zb1 += w1v * r1[64 + lane];
                }
            }
            zp[wv * E_DIM + lane] = za0 + za1;
            if (lane < E_DIM - 64) zp[wv * E_DIM + 64 + lane] = zb0 + zb1;
        }
        __syncthreads();
        if (tid < E_DIM)
            zsh[tid] = zp[tid] + zp[E_DIM + tid] + zp[2 * E_DIM + tid] + zp[3 * E_DIM + tid];
        __syncthreads();
        if (tid < E_DIM / 2) {
            float h = b1[tid];
            for (int e = 0; e < E_DIM; ++e) h += zsh[e] * w1[e * (E_DIM / 2) + tid];
            hsh[tid] = fmaxf(h, 0.f);
        }
        __syncthreads();
    }

    if (tid < C_DIM) {
        float o = b2[tid];
#pragma unroll
        for (int j = 0; j < E_DIM / 2; ++j) o += hsh[j] * w2[j * C_DIM + tid];
        out[b * C_DIM + tid] = o;
    }
}

// ---------------------------------------------------------------------------
extern "C" void kernel_launch(void* const* d_in, const int* in_sizes, int n_in,
                              void* d_out, int out_size, void* d_ws, size_t ws_size,
                              hipStream_t stream) {
    const int*   x      = (const int*)d_in[0];
    const int*   mask   = (const int*)d_in[2];    // bool delivered as int32
    const float* emb    = (const float*)d_in[3];
    const float* labels = (const float*)d_in[4];
    const float* conv_w = (const float*)d_in[5];
    const float* conv_b = (const float*)d_in[6];
    const float* w1     = (const float*)d_in[7];
    const float* b1     = (const float*)d_in[8];
    const float* w2     = (const float*)d_in[9];
    const float* b2     = (const float*)d_in[10];
    float*       out    = (float*)d_out;

    short*    wA  = (short*)d_ws;                         // 208896 B
    float*    Lt  = (float*)((char*)d_ws + OFF_LT);
    float*    rnl = (float*)((char*)d_ws + OFF_RNL);
    float*    Wc  = (float*)((char*)d_ws + OFF_WC);
    unsigned* Gpk = (unsigned*)((char*)d_ws + OFF_GP);
    float*    EW  = (float*)((char*)d_ws + OFF_EW);

    const int prep_n = NA_SHORTS + C_DIM * E_DIM + C_DIM + E_DIM * 72;
    prep_kernel<<<(prep_n + 255) / 256, 256, 0, stream>>>(conv_w, labels, w1,
                                                          wA, Lt, rnl, Wc);

    const int vg = (V_DIM + VCH - 1) / VCH;
    if (ws_size >= NEED_FULL) {
        vocab_kernel2<true><<<vg, 256, 0, stream>>>(emb, Wc, rnl, Gpk, EW);
        fused_kernel<true, true><<<B_DIM, 256, 0, stream>>>(
            x, mask, Gpk, EW, emb, Lt, rnl, conv_b, w1, b1, w2, b2, wA, out);
    } else if (ws_size >= NEED_G) {
        vocab_kernel2<false><<<vg, 256, 0, stream>>>(emb, Wc, rnl, Gpk, EW);
        fused_kernel<true, false><<<B_DIM, 256, 0, stream>>>(
            x, mask, Gpk, EW, emb, Lt, rnl, conv_b, w1, b1, w2, b2, wA, out);
    } else {
        fused_kernel<false, false><<<B_DIM, 256, 0, stream>>>(
            x, mask, Gpk, EW, emb, Lt, rnl, conv_b, w1, b1, w2, b2, wA, out);
    }
}